// Round 14
// baseline (168.659 us; speedup 1.0000x reference)
//
#include <hip/hip_runtime.h>
#include <math.h>

#define N_NODES 50000
#define N_EDGES 1600000
#define EA (N_EDGES + N_NODES)
#define MAXD 128
#define NBUCK 196         // ceil(N_NODES / 256)
#define EPB 4096          // edges per workgroup in partition pass
#define BCAP 16000        // ebuf words per bucket (mean fill ~8163)

typedef unsigned int uint32;
typedef float f32x4 __attribute__((ext_vector_type(4)));
typedef _Float16 h16x2 __attribute__((ext_vector_type(2)));
typedef _Float16 f16x8 __attribute__((ext_vector_type(8)));

__device__ inline h16x2 u2h(uint32 u) { return __builtin_bit_cast(h16x2, u); }
__device__ inline uint32 h2u(h16x2 h) { return __builtin_bit_cast(uint32, h); }
__device__ inline uint32 pkh(float a, float b) {
  return __builtin_bit_cast(uint32, __builtin_amdgcn_cvt_pkrtz(a, b));
}
__device__ inline ushort f2h(float f) {
  _Float16 h = (_Float16)f;
  return __builtin_bit_cast(ushort, h);
}
__device__ inline int clampi(int v, int lo, int hi) {
  return v < lo ? lo : (v > hi ? hi : v);
}

// ---------------- MFMA(f16) GEMM + fused attention-logit epilogue ----------------
// C stored HEAD-BLOCKED: [2][N_NODES][N/2] fp16. al head-blocked: float2[2][N]=(src,dst).
// COPYX: also stream the f32 A rows to encout. AF16: A is head-blocked fp16 [2][N][64].
template<int N, bool AF16, bool COPYX>
__global__ __launch_bounds__(256) void gemm_mfma_kernel(
    const void* __restrict__ Ap, const float* __restrict__ B,
    const float* __restrict__ asrc, const float* __restrict__ adst,
    ushort* __restrict__ Cb, float* __restrict__ al, float* __restrict__ encout, int M) {
  constexpr int KK = 4;
  constexpr int NC = N / 16;
  constexpr int NH = N / 2;
  __shared__ uint32 Bl[KK * NC * 64 * 4];
  const int t = threadIdx.x;

  for (int id = t; id < KK * NC * 64; id += 256) {
    int lane = id & 63;
    int cf = (id >> 6) % NC;
    int kk = (id >> 6) / NC;
    int col = cf * 16 + (lane & 15);
    int k0 = kk * 32 + (lane >> 4) * 8;
    uint32 w0 = pkh(B[(k0 + 0) * N + col], B[(k0 + 1) * N + col]);
    uint32 w1 = pkh(B[(k0 + 2) * N + col], B[(k0 + 3) * N + col]);
    uint32 w2 = pkh(B[(k0 + 4) * N + col], B[(k0 + 5) * N + col]);
    uint32 w3 = pkh(B[(k0 + 6) * N + col], B[(k0 + 7) * N + col]);
    *reinterpret_cast<uint4*>(&Bl[id * 4]) = make_uint4(w0, w1, w2, w3);
  }
  __syncthreads();

  const int w = t >> 6, lane = t & 63;
  const int l15 = lane & 15, g4 = lane >> 4;
  const int row0 = blockIdx.x * 64 + w * 16;
  int arow = row0 + l15; if (arow > M - 1) arow = M - 1;
  const int k0 = g4 * 8;

  f32x4 acc[NC];
#pragma unroll
  for (int c = 0; c < NC; ++c) acc[c] = f32x4{0.f, 0.f, 0.f, 0.f};

#pragma unroll
  for (int kk = 0; kk < KK; ++kk) {
    f16x8 af;
    if (AF16) {
      int kabs = kk * 32 + k0;
      int kh = kabs >= 64;
      af = *reinterpret_cast<const f16x8*>(
          (const ushort*)Ap + (size_t)kh * N_NODES * 64 + (size_t)arow * 64 + (kabs - kh * 64));
    } else {
      const float* A = (const float*)Ap;
      float4 a0 = *reinterpret_cast<const float4*>(A + (size_t)arow * 128 + kk * 32 + k0);
      float4 a1 = *reinterpret_cast<const float4*>(A + (size_t)arow * 128 + kk * 32 + k0 + 4);
      if (COPYX) {
        *reinterpret_cast<float4*>(encout + (size_t)arow * 128 + kk * 32 + k0)     = a0;
        *reinterpret_cast<float4*>(encout + (size_t)arow * 128 + kk * 32 + k0 + 4) = a1;
      }
      union { uint32 u[4]; f16x8 v; } p;
      p.u[0] = pkh(a0.x, a0.y);
      p.u[1] = pkh(a0.z, a0.w);
      p.u[2] = pkh(a1.x, a1.y);
      p.u[3] = pkh(a1.z, a1.w);
      af = p.v;
    }
#pragma unroll
    for (int c = 0; c < NC; ++c) {
      f16x8 bf = *reinterpret_cast<const f16x8*>(&Bl[((kk * NC + c) * 64 + lane) * 4]);
      acc[c] = __builtin_amdgcn_mfma_f32_16x16x32_f16(af, bf, acc[c], 0, 0, 0);
    }
  }

  float as_c[NC], ad_c[NC];
#pragma unroll
  for (int c = 0; c < NC; ++c) { as_c[c] = asrc[c * 16 + l15]; ad_c[c] = adst[c * 16 + l15]; }
#pragma unroll
  for (int reg = 0; reg < 4; ++reg) {
    int row = row0 + g4 * 4 + reg;
    bool ok = row < M;
    float ps0 = 0.f, ps1 = 0.f, pd0 = 0.f, pd1 = 0.f;
#pragma unroll
    for (int c = 0; c < NC; ++c) {
      float v = acc[c][reg];
      if (ok) {
        int col = c * 16 + l15;
        int ch = col >= NH;
        Cb[(size_t)ch * N_NODES * NH + (size_t)row * NH + (col - ch * NH)] = f2h(v);
      }
      if (c < NC / 2) { ps0 += v * as_c[c]; pd0 += v * ad_c[c]; }
      else            { ps1 += v * as_c[c]; pd1 += v * ad_c[c]; }
    }
#pragma unroll
    for (int off = 8; off >= 1; off >>= 1) {
      ps0 += __shfl_xor(ps0, off); ps1 += __shfl_xor(ps1, off);
      pd0 += __shfl_xor(pd0, off); pd1 += __shfl_xor(pd1, off);
    }
    if (ok && l15 == 0) {
      ((float2*)al)[row]           = make_float2(ps0, pd0);   // head 0: (src, dst)
      ((float2*)al)[N_NODES + row] = make_float2(ps1, pd1);   // head 1
    }
  }
}

// ---- Pass A: partition edges into 196 coarse buckets (fixed-capacity slices) ----
// bcur pre-zeroed; slice position = b*BCAP + old count.
// staged word layout: [31:24]=bucket, [23:8]=src (<65536), [7:0]=dst&255
__global__ void partA_kernel(const int* __restrict__ src, const int* __restrict__ dst,
                             int* __restrict__ bcur, uint32* __restrict__ ebuf) {
  __shared__ int h[NBUCK];
  __shared__ int lo[NBUCK];
  __shared__ int rank_[NBUCK];     // reused as gb2 after reservation
  __shared__ uint32 staged[EPB];
  const int t = threadIdx.x;
  const int e0 = blockIdx.x * EPB;
  const int ne = min(EPB, N_EDGES - e0);

  for (int i = t; i < NBUCK; i += 256) h[i] = 0;
  __syncthreads();
  for (int i = t; i < ne; i += 256) {
    int d = dst[e0 + i];
    atomicAdd(&h[d >> 8], 1);
  }
  __syncthreads();
  if (t == 0) {
    int a = 0;
    for (int b = 0; b < NBUCK; ++b) { lo[b] = a; a += h[b]; }
  }
  __syncthreads();
  for (int i = t; i < NBUCK; i += 256) rank_[i] = lo[i];
  __syncthreads();
  for (int i = t; i < ne; i += 256) {
    int d = dst[e0 + i];
    int s = src[e0 + i];
    int b = d >> 8;
    int r = atomicAdd(&rank_[b], 1);
    staged[r] = ((uint32)b << 24) | ((uint32)s << 8) | (uint32)(d & 255);
  }
  __syncthreads();
  if (t < NBUCK) {
    int old = atomicAdd(&bcur[t], h[t]);
    rank_[t] = t * BCAP + old - lo[t];   // gb2[b]
  }
  __syncthreads();
  for (int i = t; i < ne; i += 256) {
    uint32 wd = staged[i];
    ebuf[rank_[wd >> 24] + i] = wd;
  }
}

// ---- Pass B2: per-bucket prefix base + LDS hist + scan + row_start + scatter ----
__global__ __launch_bounds__(256) void partB2_kernel(
    const int* __restrict__ bcur, const uint32* __restrict__ ebuf,
    int* __restrict__ row_start, int* __restrict__ sorted_src) {
  __shared__ uint32 sl[BCAP];
  __shared__ int h[256];
  __shared__ int cur[256];
  __shared__ int wsh[4];
  __shared__ int red[4];
  const int b = blockIdx.x;
  const int t = threadIdx.x, lane = t & 63, wv = t >> 6;
  // bbase = sum over b'<b of (count(b') + resident nodes(b'))
  int myv = 0;
  if (t < b) myv = bcur[t] + min(256, N_NODES - t * 256);
  for (int off = 32; off >= 1; off >>= 1) myv += __shfl_xor(myv, off);
  if (lane == 0) red[wv] = myv;
  h[t] = 0;
  __syncthreads();
  const int bbase = red[0] + red[1] + red[2] + red[3];
  const int base = b * BCAP;
  const int len = min(bcur[b], BCAP);
  for (int i = t; i < len; i += 256) {
    uint32 w = ebuf[base + i];
    sl[i] = w;
    atomicAdd(&h[w & 255], 1);
  }
  __syncthreads();
  const int n = b * 256 + t;
  const bool valid = n < N_NODES;
  int v = valid ? h[t] + 1 : 0;       // +1 self loop
  int x = v;
  for (int off = 1; off < 64; off <<= 1) {
    int y = __shfl_up(x, off);
    if (lane >= off) x += y;
  }
  if (lane == 63) wsh[wv] = x;
  __syncthreads();
  int wo = 0;
  for (int w = 0; w < wv; ++w) wo += wsh[w];
  int rs = bbase + wo + x - v;
  if (valid) {
    row_start[n] = rs;
    sorted_src[rs] = n;               // self loop first
    cur[t] = rs + 1;
  }
  if (b == 0 && t == 0) row_start[N_NODES] = EA;
  __syncthreads();
  for (int i = t; i < len; i += 256) {
    uint32 w = sl[i];
    int pos = atomicAdd(&cur[w & 255], 1);
    sorted_src[pos] = (int)((w >> 8) & 0xffffu);
  }
}

// ---------------- segment softmax + aggregate: ONE WAVE PER (node, head) ----------------
// Head-blocked fp16 features [2][N][HCH]; al float2[2][N]; no-max softmax; denom folded.
template<int HCH, bool OUTF16>
__global__ __launch_bounds__(256) void agg_kernel(
    const ushort* __restrict__ xh, const float* __restrict__ al,
    const int* __restrict__ row_start, const int* __restrict__ sorted_src,
    const float* __restrict__ bias, void* __restrict__ outp) {
  constexpr int RSH = HCH / 2;         // dwords per head-row
  constexpr int LPR = HCH / 8;         // lanes per row (16B each): 8 / 4
  constexpr int EPI = 64 / LPR;        // edges per step: 8 / 16
  constexpr int PF  = 32 / EPI;        // prefetch steps covering 32 edges
  __shared__ uint2 pL[4][MAXD];
  const int gw = (blockIdx.x * blockDim.x + threadIdx.x) >> 6;
  const int lane = threadIdx.x & 63;
  const int wv = (threadIdx.x >> 6) & 3;
  if (gw >= 2 * N_NODES) return;
  const int head = gw >= N_NODES ? 1 : 0;
  const int node = gw - head * N_NODES;
  const float2* alh = (const float2*)al + (size_t)head * N_NODES;
  const uint32* xb32 = (const uint32*)xh + (size_t)head * N_NODES * RSH;
  int start = row_start[node], end = row_start[node + 1];
  start = clampi(start, 0, EA);
  end   = clampi(end, start, EA);
  const int deg = end - start;
  const float adh = alh[node].y;
  const float ESH = 2.7725887f;        // 4*ln2: exact-alpha shift, no-overflow
  float dsum = 0.f;

  if (deg > MAXD) {
    // ---- fallback (cold): fp32 math with max ----
    float m = -1e30f;
    for (int i = start + lane; i < end; i += 64) {
      int s = clampi(sorted_src[i], 0, N_NODES - 1);
      float l = alh[s].x + adh; l = l > 0.f ? l : 0.2f * l;
      m = fmaxf(m, l);
    }
    for (int off = 32; off >= 1; off >>= 1) m = fmaxf(m, __shfl_xor(m, off));
    for (int i = start + lane; i < end; i += 64) {
      int s = clampi(sorted_src[i], 0, N_NODES - 1);
      float l = alh[s].x + adh; l = l > 0.f ? l : 0.2f * l;
      dsum += __expf(l - m);
    }
    for (int off = 32; off >= 1; off >>= 1) dsum += __shfl_xor(dsum, off);
    const float inv = 1.f / dsum;
    if (lane < RSH) {
      float a0 = 0.f, a1 = 0.f;
      for (int i = start; i < end; ++i) {
        int s = clampi(sorted_src[i], 0, N_NODES - 1);
        float l = alh[s].x + adh; l = l > 0.f ? l : 0.2f * l;
        float w = __expf(l - m) * inv;
        h16x2 hx = u2h(xb32[(size_t)s * RSH + lane]);
        a0 = fmaf(w, (float)hx[0], a0);
        a1 = fmaf(w, (float)hx[1], a1);
      }
      int cols0 = head * HCH + lane * 2;
      float o0 = a0 + bias[cols0];
      float o1 = a1 + bias[cols0 + 1];
      o0 = o0 > 0.f ? o0 : __expf(o0) - 1.f;
      o1 = o1 > 0.f ? o1 : __expf(o1) - 1.f;
      if (OUTF16) {
        ((uint32*)outp)[(size_t)head * N_NODES * RSH + (size_t)node * RSH + lane] = pkh(o0, o1);
      } else {
        float* op = (float*)outp + (size_t)node * (2 * HCH) + head * HCH + lane * 2;
        op[0] = o0; op[1] = o1;
      }
    }
    return;
  }

  // ---- stage (s, pkh(e,e)); accumulate denom ----
  for (int i = start + lane; i < end; i += 64) {
    int s = clampi(sorted_src[i], 0, N_NODES - 1);
    float l = alh[s].x + adh; l = l > 0.f ? l : 0.2f * l;
    float e = __expf(l - ESH);
    pL[wv][i - start] = make_uint2((uint32)s, pkh(e, e));
    dsum += e;
  }

  const int q  = lane / LPR;
  const int cc = lane % LPR;
  const uint2* myP = &pL[wv][0];
  const uint32* myx = xb32 + cc * 4;

  // ---- prefetch first PF steps (32 edges) under the denom reduce ----
  uint4 pv[PF];
  h16x2 pw[PF];
#pragma unroll
  for (int st = 0; st < PF; ++st) {
    int jj = st * EPI + q;
    int jc = jj < deg ? jj : 0;
    uint2 p = myP[jc];
    pw[st] = u2h(jj < deg ? p.y : 0u);
    pv[st] = *reinterpret_cast<const uint4*>(myx + (size_t)p.x * RSH);
  }

  for (int off = 32; off >= 1; off >>= 1) dsum += __shfl_xor(dsum, off);
  const float inv = 1.f / dsum;

  h16x2 acc2[4];
#pragma unroll
  for (int k = 0; k < 4; ++k) acc2[k] = u2h(0u);

#pragma unroll
  for (int st = 0; st < PF; ++st) {
    acc2[0] += pw[st] * u2h(pv[st].x); acc2[1] += pw[st] * u2h(pv[st].y);
    acc2[2] += pw[st] * u2h(pv[st].z); acc2[3] += pw[st] * u2h(pv[st].w);
  }

  int j = PF * EPI;   // = 32
  for (; j + 2 * EPI <= deg; j += 2 * EPI) {
    uint2 p0 = myP[j + q];
    uint2 p1 = myP[j + EPI + q];
    const uint4 v0 = *reinterpret_cast<const uint4*>(myx + (size_t)p0.x * RSH);
    const uint4 v1 = *reinterpret_cast<const uint4*>(myx + (size_t)p1.x * RSH);
    h16x2 w0 = u2h(p0.y), w1 = u2h(p1.y);
    acc2[0] += w0 * u2h(v0.x); acc2[1] += w0 * u2h(v0.y);
    acc2[2] += w0 * u2h(v0.z); acc2[3] += w0 * u2h(v0.w);
    acc2[0] += w1 * u2h(v1.x); acc2[1] += w1 * u2h(v1.y);
    acc2[2] += w1 * u2h(v1.z); acc2[3] += w1 * u2h(v1.w);
  }
  for (; j < deg; j += EPI) {
    int jj = j + q;
    int jc = jj < deg ? jj : 0;
    uint2 p = myP[jc];
    h16x2 w2 = u2h(jj < deg ? p.y : 0u);
    const uint4 v = *reinterpret_cast<const uint4*>(myx + (size_t)p.x * RSH);
    acc2[0] += w2 * u2h(v.x); acc2[1] += w2 * u2h(v.y);
    acc2[2] += w2 * u2h(v.z); acc2[3] += w2 * u2h(v.w);
  }

  // ---- reduce across edge slots ----
#pragma unroll
  for (int k = 0; k < 4; ++k) {
#pragma unroll
    for (int off = LPR; off < 64; off <<= 1)
      acc2[k] = u2h((uint32)__shfl_xor((int)h2u(acc2[k]), off)) + acc2[k];
  }

  // ---- epilogue: fold 1/denom, bias + ELU + store ----
  if (q == 0) {
    float o[8];
#pragma unroll
    for (int k = 0; k < 4; ++k) {
      o[2 * k]     = (float)acc2[k][0] * inv + bias[head * HCH + cc * 8 + 2 * k];
      o[2 * k + 1] = (float)acc2[k][1] * inv + bias[head * HCH + cc * 8 + 2 * k + 1];
    }
#pragma unroll
    for (int k = 0; k < 8; ++k) o[k] = o[k] > 0.f ? o[k] : __expf(o[k]) - 1.f;
    if (OUTF16) {
      uint4 u;
      u.x = pkh(o[0], o[1]); u.y = pkh(o[2], o[3]);
      u.z = pkh(o[4], o[5]); u.w = pkh(o[6], o[7]);
      *reinterpret_cast<uint4*>((uint32*)outp + (size_t)head * N_NODES * RSH +
                                (size_t)node * RSH + cc * 4) = u;
    } else {
      float* op = (float*)outp + (size_t)node * (2 * HCH) + head * HCH + cc * 8;
      *reinterpret_cast<float4*>(op)     = make_float4(o[0], o[1], o[2], o[3]);
      *reinterpret_cast<float4*>(op + 4) = make_float4(o[4], o[5], o[6], o[7]);
    }
  }
}

extern "C" void kernel_launch(void* const* d_in, const int* in_sizes, int n_in,
                              void* d_out, int out_size, void* d_ws, size_t ws_size,
                              hipStream_t stream) {
  const float* x      = (const float*)d_in[0];
  const int*   ei     = (const int*)d_in[1];
  const float* W1     = (const float*)d_in[2];
  const float* a_src1 = (const float*)d_in[3];
  const float* a_dst1 = (const float*)d_in[4];
  const float* b1     = (const float*)d_in[5];
  const float* W2     = (const float*)d_in[6];
  const float* a_src2 = (const float*)d_in[7];
  const float* a_dst2 = (const float*)d_in[8];
  const float* b2     = (const float*)d_in[9];
  float* out = (float*)d_out;

  char* ws = (char*)d_ws;
  size_t off = 0;
  auto alloc = [&](size_t bytes) {
    void* p = ws + off;
    off = (off + bytes + 255) & ~(size_t)255;
    return p;
  };
  ushort* xh1       = (ushort*)alloc((size_t)N_NODES * 128 * 2);  // fp16 xp1, [2][N][64]
  ushort* h1h       = (ushort*)alloc((size_t)N_NODES * 128 * 2);  // fp16 h1,  [2][N][64]
  ushort* xh2       = (ushort*)alloc((size_t)N_NODES * 64 * 2);   // fp16 xp2, [2][N][32]
  float*  al1       = (float*)alloc((size_t)N_NODES * 4 * 4);     // float2[2][N]
  float*  al2       = (float*)alloc((size_t)N_NODES * 4 * 4);
  int*    row_start = (int*)alloc((size_t)(N_NODES + 1) * 4);
  int*    bcur      = (int*)alloc(NBUCK * 4);
  int*    sorted_src= (int*)alloc((size_t)EA * 4);
  uint32* ebuf      = (uint32*)h1h;   // alias: h1h not live until agg1; 196*BCAP*4 <= 12.8MB

  const int* src = ei;
  const int* dst = ei + N_EDGES;

  const int aggBlocks  = (2 * N_NODES * 64) / 256;   // one wave per (node, head)
  const int partBlocks = (N_EDGES + EPB - 1) / EPB;
  const int gemmBlocks = (N_NODES + 63) / 64;

  // ---- CSR by destination ----
  hipMemsetAsync(bcur, 0, NBUCK * 4, stream);
  partA_kernel<<<partBlocks, 256, 0, stream>>>(src, dst, bcur, ebuf);
  partB2_kernel<<<NBUCK, 256, 0, stream>>>(bcur, ebuf, row_start, sorted_src);

  // ---- layer 1 (gemm fuses the encoded passthrough copy) ----
  gemm_mfma_kernel<128, false, true><<<gemmBlocks, 256, 0, stream>>>(
      x, W1, a_src1, a_dst1, xh1, al1, out + (size_t)N_NODES * 64, N_NODES);
  agg_kernel<64, true><<<aggBlocks, 256, 0, stream>>>(xh1, al1, row_start, sorted_src, b1, h1h);

  // ---- layer 2 ----
  gemm_mfma_kernel<64, true, false><<<gemmBlocks, 256, 0, stream>>>(
      h1h, W2, a_src2, a_dst2, xh2, al2, nullptr, N_NODES);
  agg_kernel<32, false><<<aggBlocks, 256, 0, stream>>>(xh2, al2, row_start, sorted_src, b2, out);
}

// Round 15
// 155.209 us; speedup vs baseline: 1.0867x; 1.0867x over previous
//
#include <hip/hip_runtime.h>
#include <math.h>

#define N_NODES 50000
#define N_EDGES 1600000
#define EA (N_EDGES + N_NODES)
#define MAXD 128
#define NBUCK 196         // ceil(N_NODES / 256)
#define EPB 4096          // edges per workgroup in partition pass
#define BCAP 16000        // ebuf words per bucket (mean fill ~8163)

typedef unsigned int uint32;
typedef float f32x4 __attribute__((ext_vector_type(4)));
typedef _Float16 h16x2 __attribute__((ext_vector_type(2)));
typedef _Float16 f16x8 __attribute__((ext_vector_type(8)));

__device__ inline h16x2 u2h(uint32 u) { return __builtin_bit_cast(h16x2, u); }
__device__ inline uint32 h2u(h16x2 h) { return __builtin_bit_cast(uint32, h); }
__device__ inline uint32 pkh(float a, float b) {
  return __builtin_bit_cast(uint32, __builtin_amdgcn_cvt_pkrtz(a, b));
}
__device__ inline ushort f2h(float f) {
  _Float16 h = (_Float16)f;
  return __builtin_bit_cast(ushort, h);
}
__device__ inline int clampi(int v, int lo, int hi) {
  return v < lo ? lo : (v > hi ? hi : v);
}

// ---------------- MFMA(f16) GEMM + fused attention-logit epilogue ----------------
// HBLK: C head-blocked [2][N_NODES][N/2] fp16, al float2[2][N]=(src,dst) per head.
// else: C interleaved [N_NODES][N] fp16, al float4[N]=(s0,s1,d0,d1).
// AF16: A is head-blocked fp16 [2][N_NODES][64]. COPYX: stream f32 A rows to encout.
template<int N, bool AF16, bool COPYX, bool HBLK>
__global__ __launch_bounds__(256) void gemm_mfma_kernel(
    const void* __restrict__ Ap, const float* __restrict__ B,
    const float* __restrict__ asrc, const float* __restrict__ adst,
    ushort* __restrict__ Cb, float* __restrict__ al, float* __restrict__ encout, int M) {
  constexpr int KK = 4;
  constexpr int NC = N / 16;
  constexpr int NH = N / 2;
  __shared__ uint32 Bl[KK * NC * 64 * 4];
  const int t = threadIdx.x;

  for (int id = t; id < KK * NC * 64; id += 256) {
    int lane = id & 63;
    int cf = (id >> 6) % NC;
    int kk = (id >> 6) / NC;
    int col = cf * 16 + (lane & 15);
    int k0 = kk * 32 + (lane >> 4) * 8;
    uint32 w0 = pkh(B[(k0 + 0) * N + col], B[(k0 + 1) * N + col]);
    uint32 w1 = pkh(B[(k0 + 2) * N + col], B[(k0 + 3) * N + col]);
    uint32 w2 = pkh(B[(k0 + 4) * N + col], B[(k0 + 5) * N + col]);
    uint32 w3 = pkh(B[(k0 + 6) * N + col], B[(k0 + 7) * N + col]);
    *reinterpret_cast<uint4*>(&Bl[id * 4]) = make_uint4(w0, w1, w2, w3);
  }
  __syncthreads();

  const int w = t >> 6, lane = t & 63;
  const int l15 = lane & 15, g4 = lane >> 4;
  const int row0 = blockIdx.x * 64 + w * 16;
  int arow = row0 + l15; if (arow > M - 1) arow = M - 1;
  const int k0 = g4 * 8;

  f32x4 acc[NC];
#pragma unroll
  for (int c = 0; c < NC; ++c) acc[c] = f32x4{0.f, 0.f, 0.f, 0.f};

#pragma unroll
  for (int kk = 0; kk < KK; ++kk) {
    f16x8 af;
    if (AF16) {
      int kabs = kk * 32 + k0;
      int kh = kabs >= 64;
      af = *reinterpret_cast<const f16x8*>(
          (const ushort*)Ap + (size_t)kh * N_NODES * 64 + (size_t)arow * 64 + (kabs - kh * 64));
    } else {
      const float* A = (const float*)Ap;
      float4 a0 = *reinterpret_cast<const float4*>(A + (size_t)arow * 128 + kk * 32 + k0);
      float4 a1 = *reinterpret_cast<const float4*>(A + (size_t)arow * 128 + kk * 32 + k0 + 4);
      if (COPYX) {
        *reinterpret_cast<float4*>(encout + (size_t)arow * 128 + kk * 32 + k0)     = a0;
        *reinterpret_cast<float4*>(encout + (size_t)arow * 128 + kk * 32 + k0 + 4) = a1;
      }
      union { uint32 u[4]; f16x8 v; } p;
      p.u[0] = pkh(a0.x, a0.y);
      p.u[1] = pkh(a0.z, a0.w);
      p.u[2] = pkh(a1.x, a1.y);
      p.u[3] = pkh(a1.z, a1.w);
      af = p.v;
    }
#pragma unroll
    for (int c = 0; c < NC; ++c) {
      f16x8 bf = *reinterpret_cast<const f16x8*>(&Bl[((kk * NC + c) * 64 + lane) * 4]);
      acc[c] = __builtin_amdgcn_mfma_f32_16x16x32_f16(af, bf, acc[c], 0, 0, 0);
    }
  }

  float as_c[NC], ad_c[NC];
#pragma unroll
  for (int c = 0; c < NC; ++c) { as_c[c] = asrc[c * 16 + l15]; ad_c[c] = adst[c * 16 + l15]; }
#pragma unroll
  for (int reg = 0; reg < 4; ++reg) {
    int row = row0 + g4 * 4 + reg;
    bool ok = row < M;
    float ps0 = 0.f, ps1 = 0.f, pd0 = 0.f, pd1 = 0.f;
#pragma unroll
    for (int c = 0; c < NC; ++c) {
      float v = acc[c][reg];
      if (ok) {
        int col = c * 16 + l15;
        if (HBLK) {
          int ch = col >= NH;
          Cb[(size_t)ch * N_NODES * NH + (size_t)row * NH + (col - ch * NH)] = f2h(v);
        } else {
          Cb[(size_t)row * N + col] = f2h(v);
        }
      }
      if (c < NC / 2) { ps0 += v * as_c[c]; pd0 += v * ad_c[c]; }
      else            { ps1 += v * as_c[c]; pd1 += v * ad_c[c]; }
    }
#pragma unroll
    for (int off = 8; off >= 1; off >>= 1) {
      ps0 += __shfl_xor(ps0, off); ps1 += __shfl_xor(ps1, off);
      pd0 += __shfl_xor(pd0, off); pd1 += __shfl_xor(pd1, off);
    }
    if (ok && l15 == 0) {
      if (HBLK) {
        ((float2*)al)[row]           = make_float2(ps0, pd0);   // head 0: (src, dst)
        ((float2*)al)[N_NODES + row] = make_float2(ps1, pd1);   // head 1
      } else {
        *reinterpret_cast<float4*>(&al[row * 4]) = make_float4(ps0, ps1, pd0, pd1);
      }
    }
  }
}

// ---- Pass A: partition edges into 196 coarse buckets (fixed-capacity slices) ----
__global__ void partA_kernel(const int* __restrict__ src, const int* __restrict__ dst,
                             int* __restrict__ bcur, uint32* __restrict__ ebuf) {
  __shared__ int h[NBUCK];
  __shared__ int lo[NBUCK];
  __shared__ int rank_[NBUCK];
  __shared__ uint32 staged[EPB];
  const int t = threadIdx.x;
  const int e0 = blockIdx.x * EPB;
  const int ne = min(EPB, N_EDGES - e0);

  for (int i = t; i < NBUCK; i += 256) h[i] = 0;
  __syncthreads();
  for (int i = t; i < ne; i += 256) {
    int d = dst[e0 + i];
    atomicAdd(&h[d >> 8], 1);
  }
  __syncthreads();
  if (t == 0) {
    int a = 0;
    for (int b = 0; b < NBUCK; ++b) { lo[b] = a; a += h[b]; }
  }
  __syncthreads();
  for (int i = t; i < NBUCK; i += 256) rank_[i] = lo[i];
  __syncthreads();
  for (int i = t; i < ne; i += 256) {
    int d = dst[e0 + i];
    int s = src[e0 + i];
    int b = d >> 8;
    int r = atomicAdd(&rank_[b], 1);
    staged[r] = ((uint32)b << 24) | ((uint32)s << 8) | (uint32)(d & 255);
  }
  __syncthreads();
  if (t < NBUCK) {
    int old = atomicAdd(&bcur[t], h[t]);
    rank_[t] = t * BCAP + old - lo[t];
  }
  __syncthreads();
  for (int i = t; i < ne; i += 256) {
    uint32 wd = staged[i];
    ebuf[rank_[wd >> 24] + i] = wd;
  }
}

// ---- Pass B2: per-bucket prefix base + LDS hist + scan + row_start + scatter ----
__global__ __launch_bounds__(256) void partB2_kernel(
    const int* __restrict__ bcur, const uint32* __restrict__ ebuf,
    int* __restrict__ row_start, int* __restrict__ sorted_src) {
  __shared__ uint32 sl[BCAP];
  __shared__ int h[256];
  __shared__ int cur[256];
  __shared__ int wsh[4];
  __shared__ int red[4];
  const int b = blockIdx.x;
  const int t = threadIdx.x, lane = t & 63, wv = t >> 6;
  int myv = 0;
  if (t < b) myv = bcur[t] + min(256, N_NODES - t * 256);
  for (int off = 32; off >= 1; off >>= 1) myv += __shfl_xor(myv, off);
  if (lane == 0) red[wv] = myv;
  h[t] = 0;
  __syncthreads();
  const int bbase = red[0] + red[1] + red[2] + red[3];
  const int base = b * BCAP;
  const int len = min(bcur[b], BCAP);
  for (int i = t; i < len; i += 256) {
    uint32 w = ebuf[base + i];
    sl[i] = w;
    atomicAdd(&h[w & 255], 1);
  }
  __syncthreads();
  const int n = b * 256 + t;
  const bool valid = n < N_NODES;
  int v = valid ? h[t] + 1 : 0;       // +1 self loop
  int x = v;
  for (int off = 1; off < 64; off <<= 1) {
    int y = __shfl_up(x, off);
    if (lane >= off) x += y;
  }
  if (lane == 63) wsh[wv] = x;
  __syncthreads();
  int wo = 0;
  for (int w = 0; w < wv; ++w) wo += wsh[w];
  int rs = bbase + wo + x - v;
  if (valid) {
    row_start[n] = rs;
    sorted_src[rs] = n;               // self loop first
    cur[t] = rs + 1;
  }
  if (b == 0 && t == 0) row_start[N_NODES] = EA;
  __syncthreads();
  for (int i = t; i < len; i += 256) {
    uint32 w = sl[i];
    int pos = atomicAdd(&cur[w & 255], 1);
    sorted_src[pos] = (int)((w >> 8) & 0xffffu);
  }
}

// ------------- agg LAYER 1: one wave per (node, head), head-blocked buffers -------------
template<int HCH>
__global__ __launch_bounds__(256) void agg_split_kernel(
    const ushort* __restrict__ xh, const float* __restrict__ al,
    const int* __restrict__ row_start, const int* __restrict__ sorted_src,
    const float* __restrict__ bias, ushort* __restrict__ outp) {
  constexpr int RSH = HCH / 2;         // dwords per head-row
  constexpr int LPR = HCH / 8;         // lanes per row
  constexpr int EPI = 64 / LPR;        // edges per step
  constexpr int PF  = 32 / EPI;        // prefetch steps covering 32 edges
  __shared__ uint2 pL[4][MAXD];
  const int gw = (blockIdx.x * blockDim.x + threadIdx.x) >> 6;
  const int lane = threadIdx.x & 63;
  const int wv = (threadIdx.x >> 6) & 3;
  if (gw >= 2 * N_NODES) return;
  const int head = gw >= N_NODES ? 1 : 0;
  const int node = gw - head * N_NODES;
  const float2* alh = (const float2*)al + (size_t)head * N_NODES;
  const uint32* xb32 = (const uint32*)xh + (size_t)head * N_NODES * RSH;
  int start = row_start[node], end = row_start[node + 1];
  start = clampi(start, 0, EA);
  end   = clampi(end, start, EA);
  const int deg = end - start;
  const float adh = alh[node].y;
  const float ESH = 2.7725887f;
  float dsum = 0.f;

  if (deg > MAXD) {
    float m = -1e30f;
    for (int i = start + lane; i < end; i += 64) {
      int s = clampi(sorted_src[i], 0, N_NODES - 1);
      float l = alh[s].x + adh; l = l > 0.f ? l : 0.2f * l;
      m = fmaxf(m, l);
    }
    for (int off = 32; off >= 1; off >>= 1) m = fmaxf(m, __shfl_xor(m, off));
    for (int i = start + lane; i < end; i += 64) {
      int s = clampi(sorted_src[i], 0, N_NODES - 1);
      float l = alh[s].x + adh; l = l > 0.f ? l : 0.2f * l;
      dsum += __expf(l - m);
    }
    for (int off = 32; off >= 1; off >>= 1) dsum += __shfl_xor(dsum, off);
    const float inv = 1.f / dsum;
    if (lane < RSH) {
      float a0 = 0.f, a1 = 0.f;
      for (int i = start; i < end; ++i) {
        int s = clampi(sorted_src[i], 0, N_NODES - 1);
        float l = alh[s].x + adh; l = l > 0.f ? l : 0.2f * l;
        float w = __expf(l - m) * inv;
        h16x2 hx = u2h(xb32[(size_t)s * RSH + lane]);
        a0 = fmaf(w, (float)hx[0], a0);
        a1 = fmaf(w, (float)hx[1], a1);
      }
      int cols0 = head * HCH + lane * 2;
      float o0 = a0 + bias[cols0];
      float o1 = a1 + bias[cols0 + 1];
      o0 = o0 > 0.f ? o0 : __expf(o0) - 1.f;
      o1 = o1 > 0.f ? o1 : __expf(o1) - 1.f;
      ((uint32*)outp)[(size_t)head * N_NODES * RSH + (size_t)node * RSH + lane] = pkh(o0, o1);
    }
    return;
  }

  for (int i = start + lane; i < end; i += 64) {
    int s = clampi(sorted_src[i], 0, N_NODES - 1);
    float l = alh[s].x + adh; l = l > 0.f ? l : 0.2f * l;
    float e = __expf(l - ESH);
    pL[wv][i - start] = make_uint2((uint32)s, pkh(e, e));
    dsum += e;
  }

  const int q  = lane / LPR;
  const int cc = lane % LPR;
  const uint2* myP = &pL[wv][0];
  const uint32* myx = xb32 + cc * 4;

  uint4 pv[PF];
  h16x2 pw[PF];
#pragma unroll
  for (int st = 0; st < PF; ++st) {
    int jj = st * EPI + q;
    int jc = jj < deg ? jj : 0;
    uint2 p = myP[jc];
    pw[st] = u2h(jj < deg ? p.y : 0u);
    pv[st] = *reinterpret_cast<const uint4*>(myx + (size_t)p.x * RSH);
  }

  for (int off = 32; off >= 1; off >>= 1) dsum += __shfl_xor(dsum, off);
  const float inv = 1.f / dsum;

  h16x2 acc2[4];
#pragma unroll
  for (int k = 0; k < 4; ++k) acc2[k] = u2h(0u);

#pragma unroll
  for (int st = 0; st < PF; ++st) {
    acc2[0] += pw[st] * u2h(pv[st].x); acc2[1] += pw[st] * u2h(pv[st].y);
    acc2[2] += pw[st] * u2h(pv[st].z); acc2[3] += pw[st] * u2h(pv[st].w);
  }

  int j = PF * EPI;
  for (; j + 2 * EPI <= deg; j += 2 * EPI) {
    uint2 p0 = myP[j + q];
    uint2 p1 = myP[j + EPI + q];
    const uint4 v0 = *reinterpret_cast<const uint4*>(myx + (size_t)p0.x * RSH);
    const uint4 v1 = *reinterpret_cast<const uint4*>(myx + (size_t)p1.x * RSH);
    h16x2 w0 = u2h(p0.y), w1 = u2h(p1.y);
    acc2[0] += w0 * u2h(v0.x); acc2[1] += w0 * u2h(v0.y);
    acc2[2] += w0 * u2h(v0.z); acc2[3] += w0 * u2h(v0.w);
    acc2[0] += w1 * u2h(v1.x); acc2[1] += w1 * u2h(v1.y);
    acc2[2] += w1 * u2h(v1.z); acc2[3] += w1 * u2h(v1.w);
  }
  for (; j < deg; j += EPI) {
    int jj = j + q;
    int jc = jj < deg ? jj : 0;
    uint2 p = myP[jc];
    h16x2 w2 = u2h(jj < deg ? p.y : 0u);
    const uint4 v = *reinterpret_cast<const uint4*>(myx + (size_t)p.x * RSH);
    acc2[0] += w2 * u2h(v.x); acc2[1] += w2 * u2h(v.y);
    acc2[2] += w2 * u2h(v.z); acc2[3] += w2 * u2h(v.w);
  }

#pragma unroll
  for (int k = 0; k < 4; ++k) {
#pragma unroll
    for (int off = LPR; off < 64; off <<= 1)
      acc2[k] = u2h((uint32)__shfl_xor((int)h2u(acc2[k]), off)) + acc2[k];
  }

  if (q == 0) {
    float o[8];
#pragma unroll
    for (int k = 0; k < 4; ++k) {
      o[2 * k]     = (float)acc2[k][0] * inv + bias[head * HCH + cc * 8 + 2 * k];
      o[2 * k + 1] = (float)acc2[k][1] * inv + bias[head * HCH + cc * 8 + 2 * k + 1];
    }
#pragma unroll
    for (int k = 0; k < 8; ++k) o[k] = o[k] > 0.f ? o[k] : __expf(o[k]) - 1.f;
    uint4 u;
    u.x = pkh(o[0], o[1]); u.y = pkh(o[2], o[3]);
    u.z = pkh(o[4], o[5]); u.w = pkh(o[6], o[7]);
    *reinterpret_cast<uint4*>((uint32*)outp + (size_t)head * N_NODES * RSH +
                              (size_t)node * RSH + cc * 4) = u;
  }
}

// ------------- agg LAYER 2: one wave per node, interleaved buffers, f32 out -------------
// xh [N][64] fp16 (128B rows); al float4[N]; out f32 [N][64].
__global__ __launch_bounds__(256) void agg_full_kernel(
    const ushort* __restrict__ xh, const float* __restrict__ al,
    const int* __restrict__ row_start, const int* __restrict__ sorted_src,
    const float* __restrict__ bias, float* __restrict__ outp) {
  constexpr int HC = 64;
  constexpr int LPR = HC / 8;          // 8 lanes per 128B row
  constexpr int EPI = 64 / LPR;        // 8 edges per step
  constexpr int RS  = HC / 2;          // 32 dwords per row
  constexpr int PF  = 4;               // 32 edges prefetched
  __shared__ uint2 pL[4][2][MAXD];
  const int wid = (blockIdx.x * blockDim.x + threadIdx.x) >> 6;
  const int lane = threadIdx.x & 63;
  const int wv = (threadIdx.x >> 6) & 3;
  if (wid >= N_NODES) return;
  const float4* al4 = (const float4*)al;
  const uint32* xb32 = (const uint32*)xh;
  int start = row_start[wid], end = row_start[wid + 1];
  start = clampi(start, 0, EA);
  end   = clampi(end, start, EA);
  const int deg = end - start;
  float4 mya = al4[wid];
  const float ad0 = mya.z, ad1 = mya.w;
  const float ESH = 2.7725887f;
  float d0 = 0.f, d1 = 0.f;

  if (deg > MAXD) {
    float m0 = -1e30f, m1 = -1e30f;
    for (int i = start + lane; i < end; i += 64) {
      int s = clampi(sorted_src[i], 0, N_NODES - 1);
      float4 a = al4[s];
      float l0 = a.x + ad0; l0 = l0 > 0.f ? l0 : 0.2f * l0;
      float l1 = a.y + ad1; l1 = l1 > 0.f ? l1 : 0.2f * l1;
      m0 = fmaxf(m0, l0); m1 = fmaxf(m1, l1);
    }
    for (int off = 32; off >= 1; off >>= 1) {
      m0 = fmaxf(m0, __shfl_xor(m0, off));
      m1 = fmaxf(m1, __shfl_xor(m1, off));
    }
    for (int i = start + lane; i < end; i += 64) {
      int s = clampi(sorted_src[i], 0, N_NODES - 1);
      float4 a = al4[s];
      float l0 = a.x + ad0; l0 = l0 > 0.f ? l0 : 0.2f * l0;
      float l1 = a.y + ad1; l1 = l1 > 0.f ? l1 : 0.2f * l1;
      d0 += __expf(l0 - m0); d1 += __expf(l1 - m1);
    }
    for (int off = 32; off >= 1; off >>= 1) {
      d0 += __shfl_xor(d0, off);
      d1 += __shfl_xor(d1, off);
    }
    const float inv0 = 1.f / d0, inv1 = 1.f / d1;
    const int cols0 = lane * 2;
    const int head = cols0 >= 32;   // NOTE: 32 cols per head
    const float invh = head ? inv1 : inv0;
    const float mh = head ? m1 : m0;
    const float adh = head ? ad1 : ad0;
    float a0 = 0.f, a1 = 0.f;
    if (lane < RS) {
      for (int i = start; i < end; ++i) {
        int s = clampi(sorted_src[i], 0, N_NODES - 1);
        float lv = (head ? al4[s].y : al4[s].x) + adh;
        lv = lv > 0.f ? lv : 0.2f * lv;
        float w = __expf(lv - mh) * invh;
        h16x2 hx = u2h(xb32[(size_t)s * RS + lane]);
        a0 = fmaf(w, (float)hx[0], a0);
        a1 = fmaf(w, (float)hx[1], a1);
      }
      float o0 = a0 + bias[cols0];
      float o1 = a1 + bias[cols0 + 1];
      o0 = o0 > 0.f ? o0 : __expf(o0) - 1.f;
      o1 = o1 > 0.f ? o1 : __expf(o1) - 1.f;
      *reinterpret_cast<float2*>(outp + (size_t)wid * HC + cols0) = make_float2(o0, o1);
    }
    return;
  }

  // ---- stage both heads: (s, pkh(e,e)) each; accumulate denoms ----
  for (int i = start + lane; i < end; i += 64) {
    int s = clampi(sorted_src[i], 0, N_NODES - 1);
    float4 a = al4[s];
    float l0 = a.x + ad0; l0 = l0 > 0.f ? l0 : 0.2f * l0;
    float l1 = a.y + ad1; l1 = l1 > 0.f ? l1 : 0.2f * l1;
    float e0 = __expf(l0 - ESH);
    float e1 = __expf(l1 - ESH);
    int j = i - start;
    pL[wv][0][j] = make_uint2((uint32)s, pkh(e0, e0));
    pL[wv][1][j] = make_uint2((uint32)s, pkh(e1, e1));
    d0 += e0; d1 += e1;
  }

  const int q  = lane / LPR;
  const int cc = lane % LPR;
  const int hd = cc / (LPR / 2);       // cols [0,32) head0, [32,64) head1
  const uint2* myP = &pL[wv][hd][0];
  const uint32* myx = xb32 + cc * 4;

  uint4 pv[PF];
  h16x2 pw[PF];
#pragma unroll
  for (int st = 0; st < PF; ++st) {
    int jj = st * EPI + q;
    int jc = jj < deg ? jj : 0;
    uint2 p = myP[jc];
    pw[st] = u2h(jj < deg ? p.y : 0u);
    pv[st] = *reinterpret_cast<const uint4*>(myx + (size_t)p.x * RS);
  }

  for (int off = 32; off >= 1; off >>= 1) {
    d0 += __shfl_xor(d0, off);
    d1 += __shfl_xor(d1, off);
  }
  const float inv0 = 1.f / d0, inv1 = 1.f / d1;

  h16x2 acc2[4];
#pragma unroll
  for (int k = 0; k < 4; ++k) acc2[k] = u2h(0u);

#pragma unroll
  for (int st = 0; st < PF; ++st) {
    acc2[0] += pw[st] * u2h(pv[st].x); acc2[1] += pw[st] * u2h(pv[st].y);
    acc2[2] += pw[st] * u2h(pv[st].z); acc2[3] += pw[st] * u2h(pv[st].w);
  }

  int j = PF * EPI;
  for (; j + 2 * EPI <= deg; j += 2 * EPI) {
    uint2 p0 = myP[j + q];
    uint2 p1 = myP[j + EPI + q];
    const uint4 v0 = *reinterpret_cast<const uint4*>(myx + (size_t)p0.x * RS);
    const uint4 v1 = *reinterpret_cast<const uint4*>(myx + (size_t)p1.x * RS);
    h16x2 w0 = u2h(p0.y), w1 = u2h(p1.y);
    acc2[0] += w0 * u2h(v0.x); acc2[1] += w0 * u2h(v0.y);
    acc2[2] += w0 * u2h(v0.z); acc2[3] += w0 * u2h(v0.w);
    acc2[0] += w1 * u2h(v1.x); acc2[1] += w1 * u2h(v1.y);
    acc2[2] += w1 * u2h(v1.z); acc2[3] += w1 * u2h(v1.w);
  }
  for (; j < deg; j += EPI) {
    int jj = j + q;
    int jc = jj < deg ? jj : 0;
    uint2 p = myP[jc];
    h16x2 w2 = u2h(jj < deg ? p.y : 0u);
    const uint4 v = *reinterpret_cast<const uint4*>(myx + (size_t)p.x * RS);
    acc2[0] += w2 * u2h(v.x); acc2[1] += w2 * u2h(v.y);
    acc2[2] += w2 * u2h(v.z); acc2[3] += w2 * u2h(v.w);
  }

#pragma unroll
  for (int k = 0; k < 4; ++k) {
#pragma unroll
    for (int off = LPR; off < 64; off <<= 1)
      acc2[k] = u2h((uint32)__shfl_xor((int)h2u(acc2[k]), off)) + acc2[k];
  }

  if (q == 0) {
    const float invh = hd ? inv1 : inv0;
    float o[8];
#pragma unroll
    for (int k = 0; k < 4; ++k) {
      o[2 * k]     = (float)acc2[k][0] * invh + bias[cc * 8 + 2 * k];
      o[2 * k + 1] = (float)acc2[k][1] * invh + bias[cc * 8 + 2 * k + 1];
    }
#pragma unroll
    for (int k = 0; k < 8; ++k) o[k] = o[k] > 0.f ? o[k] : __expf(o[k]) - 1.f;
    float* op = outp + (size_t)wid * HC + cc * 8;
    *reinterpret_cast<float4*>(op)     = make_float4(o[0], o[1], o[2], o[3]);
    *reinterpret_cast<float4*>(op + 4) = make_float4(o[4], o[5], o[6], o[7]);
  }
}

extern "C" void kernel_launch(void* const* d_in, const int* in_sizes, int n_in,
                              void* d_out, int out_size, void* d_ws, size_t ws_size,
                              hipStream_t stream) {
  const float* x      = (const float*)d_in[0];
  const int*   ei     = (const int*)d_in[1];
  const float* W1     = (const float*)d_in[2];
  const float* a_src1 = (const float*)d_in[3];
  const float* a_dst1 = (const float*)d_in[4];
  const float* b1     = (const float*)d_in[5];
  const float* W2     = (const float*)d_in[6];
  const float* a_src2 = (const float*)d_in[7];
  const float* a_dst2 = (const float*)d_in[8];
  const float* b2     = (const float*)d_in[9];
  float* out = (float*)d_out;

  char* ws = (char*)d_ws;
  size_t off = 0;
  auto alloc = [&](size_t bytes) {
    void* p = ws + off;
    off = (off + bytes + 255) & ~(size_t)255;
    return p;
  };
  ushort* xh1       = (ushort*)alloc((size_t)N_NODES * 128 * 2);  // fp16 xp1, [2][N][64]
  ushort* h1h       = (ushort*)alloc((size_t)N_NODES * 128 * 2);  // fp16 h1,  [2][N][64]
  ushort* xh2       = (ushort*)alloc((size_t)N_NODES * 64 * 2);   // fp16 xp2, [N][64]
  float*  al1       = (float*)alloc((size_t)N_NODES * 4 * 4);     // float2[2][N]
  float*  al2       = (float*)alloc((size_t)N_NODES * 4 * 4);     // float4[N]
  int*    row_start = (int*)alloc((size_t)(N_NODES + 1) * 4);
  int*    bcur      = (int*)alloc(NBUCK * 4);
  int*    sorted_src= (int*)alloc((size_t)EA * 4);
  uint32* ebuf      = (uint32*)h1h;   // alias: h1h not live until agg1

  const int* src = ei;
  const int* dst = ei + N_EDGES;

  const int agg1Blocks = (2 * N_NODES * 64) / 256;   // one wave per (node, head)
  const int agg2Blocks = (N_NODES * 64) / 256;       // one wave per node
  const int partBlocks = (N_EDGES + EPB - 1) / EPB;
  const int gemmBlocks = (N_NODES + 63) / 64;

  // ---- CSR by destination ----
  hipMemsetAsync(bcur, 0, NBUCK * 4, stream);
  partA_kernel<<<partBlocks, 256, 0, stream>>>(src, dst, bcur, ebuf);
  partB2_kernel<<<NBUCK, 256, 0, stream>>>(bcur, ebuf, row_start, sorted_src);

  // ---- layer 1: head-blocked (agg1 head-split waves for L2 locality) ----
  gemm_mfma_kernel<128, false, true, true><<<gemmBlocks, 256, 0, stream>>>(
      x, W1, a_src1, a_dst1, xh1, al1, out + (size_t)N_NODES * 64, N_NODES);
  agg_split_kernel<64><<<agg1Blocks, 256, 0, stream>>>(xh1, al1, row_start, sorted_src, b1, h1h);

  // ---- layer 2: interleaved (single wave per node; small working set) ----
  gemm_mfma_kernel<64, true, false, false><<<gemmBlocks, 256, 0, stream>>>(
      h1h, W2, a_src2, a_dst2, xh2, al2, nullptr, N_NODES);
  agg_full_kernel<<<agg2Blocks, 256, 0, stream>>>(xh2, al2, row_start, sorted_src, b2, out);
}

// Round 16
// 153.683 us; speedup vs baseline: 1.0975x; 1.0099x over previous
//
#include <hip/hip_runtime.h>
#include <math.h>

#define N_NODES 50000
#define N_EDGES 1600000
#define EA (N_EDGES + N_NODES)
#define NBUCK 196         // ceil(N_NODES / 256)
#define EPB 4096          // edges per workgroup in partition pass
#define BCAP 16000        // ebuf words per bucket (mean fill ~8163)

typedef unsigned int uint32;
typedef float f32x4 __attribute__((ext_vector_type(4)));
typedef _Float16 h16x2 __attribute__((ext_vector_type(2)));
typedef _Float16 f16x8 __attribute__((ext_vector_type(8)));

__device__ inline h16x2 u2h(uint32 u) { return __builtin_bit_cast(h16x2, u); }
__device__ inline uint32 h2u(h16x2 h) { return __builtin_bit_cast(uint32, h); }
__device__ inline uint32 pkh(float a, float b) {
  return __builtin_bit_cast(uint32, __builtin_amdgcn_cvt_pkrtz(a, b));
}
__device__ inline ushort f2h(float f) {
  _Float16 h = (_Float16)f;
  return __builtin_bit_cast(ushort, h);
}
__device__ inline int clampi(int v, int lo, int hi) {
  return v < lo ? lo : (v > hi ? hi : v);
}

// ---------------- MFMA(f16) GEMM + fused attention-logit epilogue ----------------
// HBLK: C head-blocked [2][N_NODES][N/2] fp16, al float2[2][N]=(src,dst) per head.
// else: C interleaved [N_NODES][N] fp16, al float4[N]=(s0,s1,d0,d1).
// AF16: A is head-blocked fp16 [2][N_NODES][64]. COPYX: stream f32 A rows to encout.
template<int N, bool AF16, bool COPYX, bool HBLK>
__global__ __launch_bounds__(256) void gemm_mfma_kernel(
    const void* __restrict__ Ap, const float* __restrict__ B,
    const float* __restrict__ asrc, const float* __restrict__ adst,
    ushort* __restrict__ Cb, float* __restrict__ al, float* __restrict__ encout, int M) {
  constexpr int KK = 4;
  constexpr int NC = N / 16;
  constexpr int NH = N / 2;
  __shared__ uint32 Bl[KK * NC * 64 * 4];
  const int t = threadIdx.x;

  for (int id = t; id < KK * NC * 64; id += 256) {
    int lane = id & 63;
    int cf = (id >> 6) % NC;
    int kk = (id >> 6) / NC;
    int col = cf * 16 + (lane & 15);
    int k0 = kk * 32 + (lane >> 4) * 8;
    uint32 w0 = pkh(B[(k0 + 0) * N + col], B[(k0 + 1) * N + col]);
    uint32 w1 = pkh(B[(k0 + 2) * N + col], B[(k0 + 3) * N + col]);
    uint32 w2 = pkh(B[(k0 + 4) * N + col], B[(k0 + 5) * N + col]);
    uint32 w3 = pkh(B[(k0 + 6) * N + col], B[(k0 + 7) * N + col]);
    *reinterpret_cast<uint4*>(&Bl[id * 4]) = make_uint4(w0, w1, w2, w3);
  }
  __syncthreads();

  const int w = t >> 6, lane = t & 63;
  const int l15 = lane & 15, g4 = lane >> 4;
  const int row0 = blockIdx.x * 64 + w * 16;
  int arow = row0 + l15; if (arow > M - 1) arow = M - 1;
  const int k0 = g4 * 8;

  f32x4 acc[NC];
#pragma unroll
  for (int c = 0; c < NC; ++c) acc[c] = f32x4{0.f, 0.f, 0.f, 0.f};

#pragma unroll
  for (int kk = 0; kk < KK; ++kk) {
    f16x8 af;
    if (AF16) {
      int kabs = kk * 32 + k0;
      int kh = kabs >= 64;
      af = *reinterpret_cast<const f16x8*>(
          (const ushort*)Ap + (size_t)kh * N_NODES * 64 + (size_t)arow * 64 + (kabs - kh * 64));
    } else {
      const float* A = (const float*)Ap;
      float4 a0 = *reinterpret_cast<const float4*>(A + (size_t)arow * 128 + kk * 32 + k0);
      float4 a1 = *reinterpret_cast<const float4*>(A + (size_t)arow * 128 + kk * 32 + k0 + 4);
      if (COPYX) {
        *reinterpret_cast<float4*>(encout + (size_t)arow * 128 + kk * 32 + k0)     = a0;
        *reinterpret_cast<float4*>(encout + (size_t)arow * 128 + kk * 32 + k0 + 4) = a1;
      }
      union { uint32 u[4]; f16x8 v; } p;
      p.u[0] = pkh(a0.x, a0.y);
      p.u[1] = pkh(a0.z, a0.w);
      p.u[2] = pkh(a1.x, a1.y);
      p.u[3] = pkh(a1.z, a1.w);
      af = p.v;
    }
#pragma unroll
    for (int c = 0; c < NC; ++c) {
      f16x8 bf = *reinterpret_cast<const f16x8*>(&Bl[((kk * NC + c) * 64 + lane) * 4]);
      acc[c] = __builtin_amdgcn_mfma_f32_16x16x32_f16(af, bf, acc[c], 0, 0, 0);
    }
  }

  float as_c[NC], ad_c[NC];
#pragma unroll
  for (int c = 0; c < NC; ++c) { as_c[c] = asrc[c * 16 + l15]; ad_c[c] = adst[c * 16 + l15]; }
#pragma unroll
  for (int reg = 0; reg < 4; ++reg) {
    int row = row0 + g4 * 4 + reg;
    bool ok = row < M;
    float ps0 = 0.f, ps1 = 0.f, pd0 = 0.f, pd1 = 0.f;
#pragma unroll
    for (int c = 0; c < NC; ++c) {
      float v = acc[c][reg];
      if (ok) {
        int col = c * 16 + l15;
        if (HBLK) {
          int ch = col >= NH;
          Cb[(size_t)ch * N_NODES * NH + (size_t)row * NH + (col - ch * NH)] = f2h(v);
        } else {
          Cb[(size_t)row * N + col] = f2h(v);
        }
      }
      if (c < NC / 2) { ps0 += v * as_c[c]; pd0 += v * ad_c[c]; }
      else            { ps1 += v * as_c[c]; pd1 += v * ad_c[c]; }
    }
#pragma unroll
    for (int off = 8; off >= 1; off >>= 1) {
      ps0 += __shfl_xor(ps0, off); ps1 += __shfl_xor(ps1, off);
      pd0 += __shfl_xor(pd0, off); pd1 += __shfl_xor(pd1, off);
    }
    if (ok && l15 == 0) {
      if (HBLK) {
        ((float2*)al)[row]           = make_float2(ps0, pd0);   // head 0: (src, dst)
        ((float2*)al)[N_NODES + row] = make_float2(ps1, pd1);   // head 1
      } else {
        *reinterpret_cast<float4*>(&al[row * 4]) = make_float4(ps0, ps1, pd0, pd1);
      }
    }
  }
}

// ---- Pass A: partition edges into 196 coarse buckets (fixed-capacity slices) ----
__global__ void partA_kernel(const int* __restrict__ src, const int* __restrict__ dst,
                             int* __restrict__ bcur, uint32* __restrict__ ebuf) {
  __shared__ int h[NBUCK];
  __shared__ int lo[NBUCK];
  __shared__ int rank_[NBUCK];
  __shared__ uint32 staged[EPB];
  const int t = threadIdx.x;
  const int e0 = blockIdx.x * EPB;
  const int ne = min(EPB, N_EDGES - e0);

  for (int i = t; i < NBUCK; i += 256) h[i] = 0;
  __syncthreads();
  for (int i = t; i < ne; i += 256) {
    int d = dst[e0 + i];
    atomicAdd(&h[d >> 8], 1);
  }
  __syncthreads();
  if (t == 0) {
    int a = 0;
    for (int b = 0; b < NBUCK; ++b) { lo[b] = a; a += h[b]; }
  }
  __syncthreads();
  for (int i = t; i < NBUCK; i += 256) rank_[i] = lo[i];
  __syncthreads();
  for (int i = t; i < ne; i += 256) {
    int d = dst[e0 + i];
    int s = src[e0 + i];
    int b = d >> 8;
    int r = atomicAdd(&rank_[b], 1);
    staged[r] = ((uint32)b << 24) | ((uint32)s << 8) | (uint32)(d & 255);
  }
  __syncthreads();
  if (t < NBUCK) {
    int old = atomicAdd(&bcur[t], h[t]);
    rank_[t] = t * BCAP + old - lo[t];
  }
  __syncthreads();
  for (int i = t; i < ne; i += 256) {
    uint32 wd = staged[i];
    ebuf[rank_[wd >> 24] + i] = wd;
  }
}

// ---- Pass B2: per-bucket prefix base + LDS hist + scan + row_start + scatter ----
__global__ __launch_bounds__(256) void partB2_kernel(
    const int* __restrict__ bcur, const uint32* __restrict__ ebuf,
    int* __restrict__ row_start, int* __restrict__ sorted_src) {
  __shared__ uint32 sl[BCAP];
  __shared__ int h[256];
  __shared__ int cur[256];
  __shared__ int wsh[4];
  __shared__ int red[4];
  const int b = blockIdx.x;
  const int t = threadIdx.x, lane = t & 63, wv = t >> 6;
  int myv = 0;
  if (t < b) myv = bcur[t] + min(256, N_NODES - t * 256);
  for (int off = 32; off >= 1; off >>= 1) myv += __shfl_xor(myv, off);
  if (lane == 0) red[wv] = myv;
  h[t] = 0;
  __syncthreads();
  const int bbase = red[0] + red[1] + red[2] + red[3];
  const int base = b * BCAP;
  const int len = min(bcur[b], BCAP);
  for (int i = t; i < len; i += 256) {
    uint32 w = ebuf[base + i];
    sl[i] = w;
    atomicAdd(&h[w & 255], 1);
  }
  __syncthreads();
  const int n = b * 256 + t;
  const bool valid = n < N_NODES;
  int v = valid ? h[t] + 1 : 0;       // +1 self loop
  int x = v;
  for (int off = 1; off < 64; off <<= 1) {
    int y = __shfl_up(x, off);
    if (lane >= off) x += y;
  }
  if (lane == 63) wsh[wv] = x;
  __syncthreads();
  int wo = 0;
  for (int w = 0; w < wv; ++w) wo += wsh[w];
  int rs = bbase + wo + x - v;
  if (valid) {
    row_start[n] = rs;
    sorted_src[rs] = n;               // self loop first
    cur[t] = rs + 1;
  }
  if (b == 0 && t == 0) row_start[N_NODES] = EA;
  __syncthreads();
  for (int i = t; i < len; i += 256) {
    uint32 w = sl[i];
    int pos = atomicAdd(&cur[w & 255], 1);
    sorted_src[pos] = (int)((w >> 8) & 0xffffu);
  }
}

// ------------- agg LAYER 1: one wave per (node, head), head-blocked buffers -------------
// deg<=64 fast path: edges register-resident (lane j owns edge j), shfl broadcasts, no LDS.
template<int HCH>
__global__ __launch_bounds__(256) void agg_split_kernel(
    const ushort* __restrict__ xh, const float* __restrict__ al,
    const int* __restrict__ row_start, const int* __restrict__ sorted_src,
    const float* __restrict__ bias, ushort* __restrict__ outp) {
  constexpr int RSH = HCH / 2;         // dwords per head-row (32)
  constexpr int LPR = HCH / 8;         // lanes per row (8)
  constexpr int EPI = 64 / LPR;        // edges per step (8)
  const int gw = (blockIdx.x * blockDim.x + threadIdx.x) >> 6;
  const int lane = threadIdx.x & 63;
  if (gw >= 2 * N_NODES) return;
  const int head = gw >= N_NODES ? 1 : 0;
  const int node = gw - head * N_NODES;
  const float2* alh = (const float2*)al + (size_t)head * N_NODES;
  const uint32* xb32 = (const uint32*)xh + (size_t)head * N_NODES * RSH;
  int start = row_start[node], end = row_start[node + 1];
  start = clampi(start, 0, EA);
  end   = clampi(end, start, EA);
  const int deg = end - start;
  const float adh = alh[node].y;
  const float ESH = 2.7725887f;

  if (deg > 64) {
    // ---- fallback (cold): fp32 recompute with max ----
    float m = -1e30f, dsum = 0.f;
    for (int i = start + lane; i < end; i += 64) {
      int s = clampi(sorted_src[i], 0, N_NODES - 1);
      float l = alh[s].x + adh; l = fmaxf(l, 0.2f * l);
      m = fmaxf(m, l);
    }
    for (int off = 32; off >= 1; off >>= 1) m = fmaxf(m, __shfl_xor(m, off));
    for (int i = start + lane; i < end; i += 64) {
      int s = clampi(sorted_src[i], 0, N_NODES - 1);
      float l = alh[s].x + adh; l = fmaxf(l, 0.2f * l);
      dsum += __expf(l - m);
    }
    for (int off = 32; off >= 1; off >>= 1) dsum += __shfl_xor(dsum, off);
    const float inv = 1.f / dsum;
    if (lane < RSH) {
      float a0 = 0.f, a1 = 0.f;
      for (int i = start; i < end; ++i) {
        int s = clampi(sorted_src[i], 0, N_NODES - 1);
        float l = alh[s].x + adh; l = fmaxf(l, 0.2f * l);
        float w = __expf(l - m) * inv;
        h16x2 hx = u2h(xb32[(size_t)s * RSH + lane]);
        a0 = fmaf(w, (float)hx[0], a0);
        a1 = fmaf(w, (float)hx[1], a1);
      }
      int cols0 = head * HCH + lane * 2;
      float o0 = a0 + bias[cols0];
      float o1 = a1 + bias[cols0 + 1];
      o0 = o0 > 0.f ? o0 : __expf(o0) - 1.f;
      o1 = o1 > 0.f ? o1 : __expf(o1) - 1.f;
      ((uint32*)outp)[(size_t)head * N_NODES * RSH + (size_t)node * RSH + lane] = pkh(o0, o1);
    }
    return;
  }

  // ---- register stage: lane j owns edge j (w=0 on idle lanes kills all tail selects) ----
  uint32 s_reg = 0, wpk = 0;
  float e = 0.f;
  {
    int i = start + lane;
    if (i < end) {
      int s = clampi(sorted_src[i], 0, N_NODES - 1);
      s_reg = (uint32)s;
      float l = alh[s].x + adh;
      l = fmaxf(l, 0.2f * l);
      e = __expf(l - ESH);
      wpk = pkh(e, e);
    }
  }
  float dsum = e;
  for (int off = 32; off >= 1; off >>= 1) dsum += __shfl_xor(dsum, off);
  const float inv = 1.f / dsum;

  const int q  = lane / LPR;
  const int cc = lane % LPR;
  const uint32* myx = xb32 + cc * 4;

  h16x2 acc2[4];
#pragma unroll
  for (int k = 0; k < 4; ++k) acc2[k] = u2h(0u);

  // ---- batch 0: edges 0..31 (4 steps × EPI) ----
  {
    int b0 = q, b1 = q + EPI, b2 = q + 2 * EPI, b3 = q + 3 * EPI;
    uint32 s0 = (uint32)__shfl((int)s_reg, b0), w0 = (uint32)__shfl((int)wpk, b0);
    uint32 s1 = (uint32)__shfl((int)s_reg, b1), w1 = (uint32)__shfl((int)wpk, b1);
    uint32 s2 = (uint32)__shfl((int)s_reg, b2), w2 = (uint32)__shfl((int)wpk, b2);
    uint32 s3 = (uint32)__shfl((int)s_reg, b3), w3 = (uint32)__shfl((int)wpk, b3);
    const uint4 v0 = *reinterpret_cast<const uint4*>(myx + (size_t)s0 * RSH);
    const uint4 v1 = *reinterpret_cast<const uint4*>(myx + (size_t)s1 * RSH);
    const uint4 v2 = *reinterpret_cast<const uint4*>(myx + (size_t)s2 * RSH);
    const uint4 v3 = *reinterpret_cast<const uint4*>(myx + (size_t)s3 * RSH);
    h16x2 h0 = u2h(w0), h1 = u2h(w1), h2 = u2h(w2), h3 = u2h(w3);
    acc2[0] += h0 * u2h(v0.x); acc2[1] += h0 * u2h(v0.y);
    acc2[2] += h0 * u2h(v0.z); acc2[3] += h0 * u2h(v0.w);
    acc2[0] += h1 * u2h(v1.x); acc2[1] += h1 * u2h(v1.y);
    acc2[2] += h1 * u2h(v1.z); acc2[3] += h1 * u2h(v1.w);
    acc2[0] += h2 * u2h(v2.x); acc2[1] += h2 * u2h(v2.y);
    acc2[2] += h2 * u2h(v2.z); acc2[3] += h2 * u2h(v2.w);
    acc2[0] += h3 * u2h(v3.x); acc2[1] += h3 * u2h(v3.y);
    acc2[2] += h3 * u2h(v3.z); acc2[3] += h3 * u2h(v3.w);
  }
  // ---- batch 1: edges 32..63 ----
  if (deg > 32) {
    int b0 = 32 + q, b1 = 40 + q, b2 = 48 + q, b3 = 56 + q;
    uint32 s0 = (uint32)__shfl((int)s_reg, b0), w0 = (uint32)__shfl((int)wpk, b0);
    uint32 s1 = (uint32)__shfl((int)s_reg, b1), w1 = (uint32)__shfl((int)wpk, b1);
    uint32 s2 = (uint32)__shfl((int)s_reg, b2), w2 = (uint32)__shfl((int)wpk, b2);
    uint32 s3 = (uint32)__shfl((int)s_reg, b3), w3 = (uint32)__shfl((int)wpk, b3);
    const uint4 v0 = *reinterpret_cast<const uint4*>(myx + (size_t)s0 * RSH);
    const uint4 v1 = *reinterpret_cast<const uint4*>(myx + (size_t)s1 * RSH);
    const uint4 v2 = *reinterpret_cast<const uint4*>(myx + (size_t)s2 * RSH);
    const uint4 v3 = *reinterpret_cast<const uint4*>(myx + (size_t)s3 * RSH);
    h16x2 h0 = u2h(w0), h1 = u2h(w1), h2 = u2h(w2), h3 = u2h(w3);
    acc2[0] += h0 * u2h(v0.x); acc2[1] += h0 * u2h(v0.y);
    acc2[2] += h0 * u2h(v0.z); acc2[3] += h0 * u2h(v0.w);
    acc2[0] += h1 * u2h(v1.x); acc2[1] += h1 * u2h(v1.y);
    acc2[2] += h1 * u2h(v1.z); acc2[3] += h1 * u2h(v1.w);
    acc2[0] += h2 * u2h(v2.x); acc2[1] += h2 * u2h(v2.y);
    acc2[2] += h2 * u2h(v2.z); acc2[3] += h2 * u2h(v2.w);
    acc2[0] += h3 * u2h(v3.x); acc2[1] += h3 * u2h(v3.y);
    acc2[2] += h3 * u2h(v3.z); acc2[3] += h3 * u2h(v3.w);
  }

  // ---- reduce across edge slots (q groups) ----
#pragma unroll
  for (int k = 0; k < 4; ++k) {
    acc2[k] = u2h((uint32)__shfl_xor((int)h2u(acc2[k]), 8)) + acc2[k];
    acc2[k] = u2h((uint32)__shfl_xor((int)h2u(acc2[k]), 16)) + acc2[k];
    acc2[k] = u2h((uint32)__shfl_xor((int)h2u(acc2[k]), 32)) + acc2[k];
  }

  // ---- epilogue: fold 1/denom, bias + ELU + store ----
  if (q == 0) {
    float o[8];
#pragma unroll
    for (int k = 0; k < 4; ++k) {
      o[2 * k]     = (float)acc2[k][0] * inv + bias[head * HCH + cc * 8 + 2 * k];
      o[2 * k + 1] = (float)acc2[k][1] * inv + bias[head * HCH + cc * 8 + 2 * k + 1];
    }
#pragma unroll
    for (int k = 0; k < 8; ++k) o[k] = o[k] > 0.f ? o[k] : __expf(o[k]) - 1.f;
    uint4 u;
    u.x = pkh(o[0], o[1]); u.y = pkh(o[2], o[3]);
    u.z = pkh(o[4], o[5]); u.w = pkh(o[6], o[7]);
    *reinterpret_cast<uint4*>((uint32*)outp + (size_t)head * N_NODES * RSH +
                              (size_t)node * RSH + cc * 4) = u;
  }
}

// ------------- agg LAYER 2: one wave per node, interleaved buffers, f32 out -------------
// xh [N][64] fp16 (128B rows); al float4[N]; out f32 [N][64]. Register-staged edges.
__global__ __launch_bounds__(256) void agg_full_kernel(
    const ushort* __restrict__ xh, const float* __restrict__ al,
    const int* __restrict__ row_start, const int* __restrict__ sorted_src,
    const float* __restrict__ bias, float* __restrict__ outp) {
  constexpr int HC = 64;
  constexpr int LPR = HC / 8;          // 8 lanes per 128B row
  constexpr int EPI = 64 / LPR;        // 8 edges per step
  constexpr int RS  = HC / 2;          // 32 dwords per row
  const int wid = (blockIdx.x * blockDim.x + threadIdx.x) >> 6;
  const int lane = threadIdx.x & 63;
  if (wid >= N_NODES) return;
  const float4* al4 = (const float4*)al;
  const uint32* xb32 = (const uint32*)xh;
  int start = row_start[wid], end = row_start[wid + 1];
  start = clampi(start, 0, EA);
  end   = clampi(end, start, EA);
  const int deg = end - start;
  float4 mya = al4[wid];
  const float ad0 = mya.z, ad1 = mya.w;
  const float ESH = 2.7725887f;

  if (deg > 64) {
    // ---- fallback (cold): fp32 recompute with max ----
    float m0 = -1e30f, m1 = -1e30f, d0 = 0.f, d1 = 0.f;
    for (int i = start + lane; i < end; i += 64) {
      int s = clampi(sorted_src[i], 0, N_NODES - 1);
      float4 a = al4[s];
      float l0 = a.x + ad0; l0 = fmaxf(l0, 0.2f * l0);
      float l1 = a.y + ad1; l1 = fmaxf(l1, 0.2f * l1);
      m0 = fmaxf(m0, l0); m1 = fmaxf(m1, l1);
    }
    for (int off = 32; off >= 1; off >>= 1) {
      m0 = fmaxf(m0, __shfl_xor(m0, off));
      m1 = fmaxf(m1, __shfl_xor(m1, off));
    }
    for (int i = start + lane; i < end; i += 64) {
      int s = clampi(sorted_src[i], 0, N_NODES - 1);
      float4 a = al4[s];
      float l0 = a.x + ad0; l0 = fmaxf(l0, 0.2f * l0);
      float l1 = a.y + ad1; l1 = fmaxf(l1, 0.2f * l1);
      d0 += __expf(l0 - m0); d1 += __expf(l1 - m1);
    }
    for (int off = 32; off >= 1; off >>= 1) {
      d0 += __shfl_xor(d0, off);
      d1 += __shfl_xor(d1, off);
    }
    const float inv0 = 1.f / d0, inv1 = 1.f / d1;
    const int cols0 = lane * 2;
    const int head = cols0 >= 32;
    const float invh = head ? inv1 : inv0;
    const float mh = head ? m1 : m0;
    const float adh = head ? ad1 : ad0;
    if (lane < RS) {
      float a0 = 0.f, a1 = 0.f;
      for (int i = start; i < end; ++i) {
        int s = clampi(sorted_src[i], 0, N_NODES - 1);
        float lv = (head ? al4[s].y : al4[s].x) + adh;
        lv = fmaxf(lv, 0.2f * lv);
        float w = __expf(lv - mh) * invh;
        h16x2 hx = u2h(xb32[(size_t)s * RS + lane]);
        a0 = fmaf(w, (float)hx[0], a0);
        a1 = fmaf(w, (float)hx[1], a1);
      }
      float o0 = a0 + bias[cols0];
      float o1 = a1 + bias[cols0 + 1];
      o0 = o0 > 0.f ? o0 : __expf(o0) - 1.f;
      o1 = o1 > 0.f ? o1 : __expf(o1) - 1.f;
      *reinterpret_cast<float2*>(outp + (size_t)wid * HC + cols0) = make_float2(o0, o1);
    }
    return;
  }

  // ---- register stage: lane j owns edge j; both heads' weights in regs ----
  uint32 s_reg = 0, wpk0 = 0, wpk1 = 0;
  float e0 = 0.f, e1 = 0.f;
  {
    int i = start + lane;
    if (i < end) {
      int s = clampi(sorted_src[i], 0, N_NODES - 1);
      s_reg = (uint32)s;
      float4 a = al4[s];
      float l0 = a.x + ad0; l0 = fmaxf(l0, 0.2f * l0);
      float l1 = a.y + ad1; l1 = fmaxf(l1, 0.2f * l1);
      e0 = __expf(l0 - ESH);
      e1 = __expf(l1 - ESH);
      wpk0 = pkh(e0, e0);
      wpk1 = pkh(e1, e1);
    }
  }
  float d0 = e0, d1 = e1;
  for (int off = 32; off >= 1; off >>= 1) {
    d0 += __shfl_xor(d0, off);
    d1 += __shfl_xor(d1, off);
  }
  const float inv0 = 1.f / d0, inv1 = 1.f / d1;

  const int q  = lane / LPR;
  const int cc = lane % LPR;
  const int hd = cc >> 2;              // cols [0,32) head0, [32,64) head1
  const uint32* myx = xb32 + cc * 4;

  h16x2 acc2[4];
#pragma unroll
  for (int k = 0; k < 4; ++k) acc2[k] = u2h(0u);

#pragma unroll
  for (int bat = 0; bat < 2; ++bat) {
    if (bat == 1 && deg <= 32) break;
    int jb = bat * 32;
    int b0 = jb + q, b1 = jb + 8 + q, b2 = jb + 16 + q, b3 = jb + 24 + q;
    uint32 s0 = (uint32)__shfl((int)s_reg, b0);
    uint32 s1 = (uint32)__shfl((int)s_reg, b1);
    uint32 s2 = (uint32)__shfl((int)s_reg, b2);
    uint32 s3 = (uint32)__shfl((int)s_reg, b3);
    uint32 wa0 = (uint32)__shfl((int)wpk0, b0), wb0 = (uint32)__shfl((int)wpk1, b0);
    uint32 wa1 = (uint32)__shfl((int)wpk0, b1), wb1 = (uint32)__shfl((int)wpk1, b1);
    uint32 wa2 = (uint32)__shfl((int)wpk0, b2), wb2 = (uint32)__shfl((int)wpk1, b2);
    uint32 wa3 = (uint32)__shfl((int)wpk0, b3), wb3 = (uint32)__shfl((int)wpk1, b3);
    const uint4 v0 = *reinterpret_cast<const uint4*>(myx + (size_t)s0 * RS);
    const uint4 v1 = *reinterpret_cast<const uint4*>(myx + (size_t)s1 * RS);
    const uint4 v2 = *reinterpret_cast<const uint4*>(myx + (size_t)s2 * RS);
    const uint4 v3 = *reinterpret_cast<const uint4*>(myx + (size_t)s3 * RS);
    h16x2 h0 = u2h(hd ? wb0 : wa0), h1 = u2h(hd ? wb1 : wa1);
    h16x2 h2 = u2h(hd ? wb2 : wa2), h3 = u2h(hd ? wb3 : wa3);
    acc2[0] += h0 * u2h(v0.x); acc2[1] += h0 * u2h(v0.y);
    acc2[2] += h0 * u2h(v0.z); acc2[3] += h0 * u2h(v0.w);
    acc2[0] += h1 * u2h(v1.x); acc2[1] += h1 * u2h(v1.y);
    acc2[2] += h1 * u2h(v1.z); acc2[3] += h1 * u2h(v1.w);
    acc2[0] += h2 * u2h(v2.x); acc2[1] += h2 * u2h(v2.y);
    acc2[2] += h2 * u2h(v2.z); acc2[3] += h2 * u2h(v2.w);
    acc2[0] += h3 * u2h(v3.x); acc2[1] += h3 * u2h(v3.y);
    acc2[2] += h3 * u2h(v3.z); acc2[3] += h3 * u2h(v3.w);
  }

  // ---- reduce across edge slots ----
#pragma unroll
  for (int k = 0; k < 4; ++k) {
    acc2[k] = u2h((uint32)__shfl_xor((int)h2u(acc2[k]), 8)) + acc2[k];
    acc2[k] = u2h((uint32)__shfl_xor((int)h2u(acc2[k]), 16)) + acc2[k];
    acc2[k] = u2h((uint32)__shfl_xor((int)h2u(acc2[k]), 32)) + acc2[k];
  }

  // ---- epilogue: fold 1/denom, bias + ELU + store ----
  if (q == 0) {
    const float invh = hd ? inv1 : inv0;
    float o[8];
#pragma unroll
    for (int k = 0; k < 4; ++k) {
      o[2 * k]     = (float)acc2[k][0] * invh + bias[cc * 8 + 2 * k];
      o[2 * k + 1] = (float)acc2[k][1] * invh + bias[cc * 8 + 2 * k + 1];
    }
#pragma unroll
    for (int k = 0; k < 8; ++k) o[k] = o[k] > 0.f ? o[k] : __expf(o[k]) - 1.f;
    float* op = outp + (size_t)wid * HC + cc * 8;
    *reinterpret_cast<float4*>(op)     = make_float4(o[0], o[1], o[2], o[3]);
    *reinterpret_cast<float4*>(op + 4) = make_float4(o[4], o[5], o[6], o[7]);
  }
}

extern "C" void kernel_launch(void* const* d_in, const int* in_sizes, int n_in,
                              void* d_out, int out_size, void* d_ws, size_t ws_size,
                              hipStream_t stream) {
  const float* x      = (const float*)d_in[0];
  const int*   ei     = (const int*)d_in[1];
  const float* W1     = (const float*)d_in[2];
  const float* a_src1 = (const float*)d_in[3];
  const float* a_dst1 = (const float*)d_in[4];
  const float* b1     = (const float*)d_in[5];
  const float* W2     = (const float*)d_in[6];
  const float* a_src2 = (const float*)d_in[7];
  const float* a_dst2 = (const float*)d_in[8];
  const float* b2     = (const float*)d_in[9];
  float* out = (float*)d_out;

  char* ws = (char*)d_ws;
  size_t off = 0;
  auto alloc = [&](size_t bytes) {
    void* p = ws + off;
    off = (off + bytes + 255) & ~(size_t)255;
    return p;
  };
  ushort* xh1       = (ushort*)alloc((size_t)N_NODES * 128 * 2);  // fp16 xp1, [2][N][64]
  ushort* h1h       = (ushort*)alloc((size_t)N_NODES * 128 * 2);  // fp16 h1,  [2][N][64]
  ushort* xh2       = (ushort*)alloc((size_t)N_NODES * 64 * 2);   // fp16 xp2, [N][64]
  float*  al1       = (float*)alloc((size_t)N_NODES * 4 * 4);     // float2[2][N]
  float*  al2       = (float*)alloc((size_t)N_NODES * 4 * 4);     // float4[N]
  int*    row_start = (int*)alloc((size_t)(N_NODES + 1) * 4);
  int*    bcur      = (int*)alloc(NBUCK * 4);
  int*    sorted_src= (int*)alloc((size_t)EA * 4);
  uint32* ebuf      = (uint32*)h1h;   // alias: h1h not live until agg1

  const int* src = ei;
  const int* dst = ei + N_EDGES;

  const int agg1Blocks = (2 * N_NODES * 64) / 256;   // one wave per (node, head)
  const int agg2Blocks = (N_NODES * 64) / 256;       // one wave per node
  const int partBlocks = (N_EDGES + EPB - 1) / EPB;
  const int gemmBlocks = (N_NODES + 63) / 64;

  // ---- CSR by destination ----
  hipMemsetAsync(bcur, 0, NBUCK * 4, stream);
  partA_kernel<<<partBlocks, 256, 0, stream>>>(src, dst, bcur, ebuf);
  partB2_kernel<<<NBUCK, 256, 0, stream>>>(bcur, ebuf, row_start, sorted_src);

  // ---- layer 1: head-blocked (agg1 head-split waves for L2 locality) ----
  gemm_mfma_kernel<128, false, true, true><<<gemmBlocks, 256, 0, stream>>>(
      x, W1, a_src1, a_dst1, xh1, al1, out + (size_t)N_NODES * 64, N_NODES);
  agg_split_kernel<64><<<agg1Blocks, 256, 0, stream>>>(xh1, al1, row_start, sorted_src, b1, h1h);

  // ---- layer 2: interleaved (single wave per node; small working set) ----
  gemm_mfma_kernel<64, true, false, false><<<gemmBlocks, 256, 0, stream>>>(
      h1h, W2, a_src2, a_dst2, xh2, al2, nullptr, N_NODES);
  agg_full_kernel<<<agg2Blocks, 256, 0, stream>>>(xh2, al2, row_start, sorted_src, b2, out);
}

// Round 17
// 152.966 us; speedup vs baseline: 1.1026x; 1.0047x over previous
//
#include <hip/hip_runtime.h>
#include <math.h>

#define N_NODES 50000
#define N_EDGES 1600000
#define EA (N_EDGES + N_NODES)
#define NBUCK 196         // ceil(N_NODES / 256)
#define EPB 4096          // edges per workgroup in partition pass
#define BCAP 16000        // ebuf words per bucket (mean fill ~8163)

typedef unsigned int uint32;
typedef float f32x4 __attribute__((ext_vector_type(4)));
typedef _Float16 h16x2 __attribute__((ext_vector_type(2)));
typedef _Float16 f16x8 __attribute__((ext_vector_type(8)));

__device__ inline h16x2 u2h(uint32 u) { return __builtin_bit_cast(h16x2, u); }
__device__ inline uint32 h2u(h16x2 h) { return __builtin_bit_cast(uint32, h); }
__device__ inline uint32 pkh(float a, float b) {
  return __builtin_bit_cast(uint32, __builtin_amdgcn_cvt_pkrtz(a, b));
}
__device__ inline ushort f2h(float f) {
  _Float16 h = (_Float16)f;
  return __builtin_bit_cast(ushort, h);
}
__device__ inline int clampi(int v, int lo, int hi) {
  return v < lo ? lo : (v > hi ? hi : v);
}

// ---------------- MFMA(f16) GEMM + fused attention-logit epilogue ----------------
// HBLK: C head-blocked [2][N_NODES][N/2] fp16, al float2[2][N]=(src,dst) per head.
// else: C interleaved [N_NODES][N] fp16, al float4[N]=(s0,s1,d0,d1).
// AF16: A is head-blocked fp16 [2][N_NODES][64]. COPYX: stream f32 A rows to encout.
template<int N, bool AF16, bool COPYX, bool HBLK>
__global__ __launch_bounds__(256) void gemm_mfma_kernel(
    const void* __restrict__ Ap, const float* __restrict__ B,
    const float* __restrict__ asrc, const float* __restrict__ adst,
    ushort* __restrict__ Cb, float* __restrict__ al, float* __restrict__ encout, int M) {
  constexpr int KK = 4;
  constexpr int NC = N / 16;
  constexpr int NH = N / 2;
  __shared__ uint32 Bl[KK * NC * 64 * 4];
  const int t = threadIdx.x;

  for (int id = t; id < KK * NC * 64; id += 256) {
    int lane = id & 63;
    int cf = (id >> 6) % NC;
    int kk = (id >> 6) / NC;
    int col = cf * 16 + (lane & 15);
    int k0 = kk * 32 + (lane >> 4) * 8;
    uint32 w0 = pkh(B[(k0 + 0) * N + col], B[(k0 + 1) * N + col]);
    uint32 w1 = pkh(B[(k0 + 2) * N + col], B[(k0 + 3) * N + col]);
    uint32 w2 = pkh(B[(k0 + 4) * N + col], B[(k0 + 5) * N + col]);
    uint32 w3 = pkh(B[(k0 + 6) * N + col], B[(k0 + 7) * N + col]);
    *reinterpret_cast<uint4*>(&Bl[id * 4]) = make_uint4(w0, w1, w2, w3);
  }
  __syncthreads();

  const int w = t >> 6, lane = t & 63;
  const int l15 = lane & 15, g4 = lane >> 4;
  const int row0 = blockIdx.x * 64 + w * 16;
  int arow = row0 + l15; if (arow > M - 1) arow = M - 1;
  const int k0 = g4 * 8;

  f32x4 acc[NC];
#pragma unroll
  for (int c = 0; c < NC; ++c) acc[c] = f32x4{0.f, 0.f, 0.f, 0.f};

#pragma unroll
  for (int kk = 0; kk < KK; ++kk) {
    f16x8 af;
    if (AF16) {
      int kabs = kk * 32 + k0;
      int kh = kabs >= 64;
      af = *reinterpret_cast<const f16x8*>(
          (const ushort*)Ap + (size_t)kh * N_NODES * 64 + (size_t)arow * 64 + (kabs - kh * 64));
    } else {
      const float* A = (const float*)Ap;
      float4 a0 = *reinterpret_cast<const float4*>(A + (size_t)arow * 128 + kk * 32 + k0);
      float4 a1 = *reinterpret_cast<const float4*>(A + (size_t)arow * 128 + kk * 32 + k0 + 4);
      if (COPYX) {
        *reinterpret_cast<float4*>(encout + (size_t)arow * 128 + kk * 32 + k0)     = a0;
        *reinterpret_cast<float4*>(encout + (size_t)arow * 128 + kk * 32 + k0 + 4) = a1;
      }
      union { uint32 u[4]; f16x8 v; } p;
      p.u[0] = pkh(a0.x, a0.y);
      p.u[1] = pkh(a0.z, a0.w);
      p.u[2] = pkh(a1.x, a1.y);
      p.u[3] = pkh(a1.z, a1.w);
      af = p.v;
    }
#pragma unroll
    for (int c = 0; c < NC; ++c) {
      f16x8 bf = *reinterpret_cast<const f16x8*>(&Bl[((kk * NC + c) * 64 + lane) * 4]);
      acc[c] = __builtin_amdgcn_mfma_f32_16x16x32_f16(af, bf, acc[c], 0, 0, 0);
    }
  }

  float as_c[NC], ad_c[NC];
#pragma unroll
  for (int c = 0; c < NC; ++c) { as_c[c] = asrc[c * 16 + l15]; ad_c[c] = adst[c * 16 + l15]; }
#pragma unroll
  for (int reg = 0; reg < 4; ++reg) {
    int row = row0 + g4 * 4 + reg;
    bool ok = row < M;
    float ps0 = 0.f, ps1 = 0.f, pd0 = 0.f, pd1 = 0.f;
#pragma unroll
    for (int c = 0; c < NC; ++c) {
      float v = acc[c][reg];
      if (ok) {
        int col = c * 16 + l15;
        if (HBLK) {
          int ch = col >= NH;
          Cb[(size_t)ch * N_NODES * NH + (size_t)row * NH + (col - ch * NH)] = f2h(v);
        } else {
          Cb[(size_t)row * N + col] = f2h(v);
        }
      }
      if (c < NC / 2) { ps0 += v * as_c[c]; pd0 += v * ad_c[c]; }
      else            { ps1 += v * as_c[c]; pd1 += v * ad_c[c]; }
    }
#pragma unroll
    for (int off = 8; off >= 1; off >>= 1) {
      ps0 += __shfl_xor(ps0, off); ps1 += __shfl_xor(ps1, off);
      pd0 += __shfl_xor(pd0, off); pd1 += __shfl_xor(pd1, off);
    }
    if (ok && l15 == 0) {
      if (HBLK) {
        ((float2*)al)[row]           = make_float2(ps0, pd0);   // head 0: (src, dst)
        ((float2*)al)[N_NODES + row] = make_float2(ps1, pd1);   // head 1
      } else {
        *reinterpret_cast<float4*>(&al[row * 4]) = make_float4(ps0, ps1, pd0, pd1);
      }
    }
  }
}

// ---- Pass A: partition edges into 196 coarse buckets (fixed-capacity slices) ----
__global__ void partA_kernel(const int* __restrict__ src, const int* __restrict__ dst,
                             int* __restrict__ bcur, uint32* __restrict__ ebuf) {
  __shared__ int h[NBUCK];
  __shared__ int lo[NBUCK];
  __shared__ int rank_[NBUCK];
  __shared__ uint32 staged[EPB];
  const int t = threadIdx.x;
  const int e0 = blockIdx.x * EPB;
  const int ne = min(EPB, N_EDGES - e0);

  for (int i = t; i < NBUCK; i += 256) h[i] = 0;
  __syncthreads();
  for (int i = t; i < ne; i += 256) {
    int d = dst[e0 + i];
    atomicAdd(&h[d >> 8], 1);
  }
  __syncthreads();
  if (t == 0) {
    int a = 0;
    for (int b = 0; b < NBUCK; ++b) { lo[b] = a; a += h[b]; }
  }
  __syncthreads();
  for (int i = t; i < NBUCK; i += 256) rank_[i] = lo[i];
  __syncthreads();
  for (int i = t; i < ne; i += 256) {
    int d = dst[e0 + i];
    int s = src[e0 + i];
    int b = d >> 8;
    int r = atomicAdd(&rank_[b], 1);
    staged[r] = ((uint32)b << 24) | ((uint32)s << 8) | (uint32)(d & 255);
  }
  __syncthreads();
  if (t < NBUCK) {
    int old = atomicAdd(&bcur[t], h[t]);
    rank_[t] = t * BCAP + old - lo[t];
  }
  __syncthreads();
  for (int i = t; i < ne; i += 256) {
    uint32 wd = staged[i];
    ebuf[rank_[wd >> 24] + i] = wd;
  }
}

// ---- Pass B2: per-bucket prefix base + LDS hist + scan + row_start + scatter ----
__global__ __launch_bounds__(256) void partB2_kernel(
    const int* __restrict__ bcur, const uint32* __restrict__ ebuf,
    int* __restrict__ row_start, int* __restrict__ sorted_src) {
  __shared__ uint32 sl[BCAP];
  __shared__ int h[256];
  __shared__ int cur[256];
  __shared__ int wsh[4];
  __shared__ int red[4];
  const int b = blockIdx.x;
  const int t = threadIdx.x, lane = t & 63, wv = t >> 6;
  int myv = 0;
  if (t < b) myv = bcur[t] + min(256, N_NODES - t * 256);
  for (int off = 32; off >= 1; off >>= 1) myv += __shfl_xor(myv, off);
  if (lane == 0) red[wv] = myv;
  h[t] = 0;
  __syncthreads();
  const int bbase = red[0] + red[1] + red[2] + red[3];
  const int base = b * BCAP;
  const int len = min(bcur[b], BCAP);
  for (int i = t; i < len; i += 256) {
    uint32 w = ebuf[base + i];
    sl[i] = w;
    atomicAdd(&h[w & 255], 1);
  }
  __syncthreads();
  const int n = b * 256 + t;
  const bool valid = n < N_NODES;
  int v = valid ? h[t] + 1 : 0;       // +1 self loop
  int x = v;
  for (int off = 1; off < 64; off <<= 1) {
    int y = __shfl_up(x, off);
    if (lane >= off) x += y;
  }
  if (lane == 63) wsh[wv] = x;
  __syncthreads();
  int wo = 0;
  for (int w = 0; w < wv; ++w) wo += wsh[w];
  int rs = bbase + wo + x - v;
  if (valid) {
    row_start[n] = rs;
    sorted_src[rs] = n;               // self loop first
    cur[t] = rs + 1;
  }
  if (b == 0 && t == 0) row_start[N_NODES] = EA;
  __syncthreads();
  for (int i = t; i < len; i += 256) {
    uint32 w = sl[i];
    int pos = atomicAdd(&cur[w & 255], 1);
    sorted_src[pos] = (int)((w >> 8) & 0xffffu);
  }
}

// ------------- agg LAYER 1: one wave per (node, head), head-blocked buffers -------------
// XCD-partitioned: blocks with (b&7)<4 process head 0, others head 1 — each head's
// 6.4 MB gather array then lives in a disjoint 4-XCD L2 group (mapping heuristic only).
template<int HCH>
__global__ __launch_bounds__(256) void agg_split_kernel(
    const ushort* __restrict__ xh, const float* __restrict__ al,
    const int* __restrict__ row_start, const int* __restrict__ sorted_src,
    const float* __restrict__ bias, ushort* __restrict__ outp) {
  constexpr int RSH = HCH / 2;         // dwords per head-row (32)
  constexpr int LPR = HCH / 8;         // lanes per row (8)
  constexpr int EPI = 64 / LPR;        // edges per step (8)
  const int b = blockIdx.x;            // 25000 blocks = 3125 groups of 8
  const int head = (b >> 2) & 1;       // (b&7)<4 -> head0, else head1
  const int nidx = ((b >> 3) * 4 + (b & 3)) * 4 + ((threadIdx.x >> 6) & 3);
  const int lane = threadIdx.x & 63;
  if (nidx >= N_NODES) return;
  const int node = nidx;
  const float2* alh = (const float2*)al + (size_t)head * N_NODES;
  const uint32* xb32 = (const uint32*)xh + (size_t)head * N_NODES * RSH;
  int start = row_start[node], end = row_start[node + 1];
  start = clampi(start, 0, EA);
  end   = clampi(end, start, EA);
  const int deg = end - start;
  const float adh = alh[node].y;
  const float ESH = 2.7725887f;

  if (deg > 64) {
    // ---- fallback (cold): fp32 recompute with max ----
    float m = -1e30f, dsum = 0.f;
    for (int i = start + lane; i < end; i += 64) {
      int s = clampi(sorted_src[i], 0, N_NODES - 1);
      float l = alh[s].x + adh; l = fmaxf(l, 0.2f * l);
      m = fmaxf(m, l);
    }
    for (int off = 32; off >= 1; off >>= 1) m = fmaxf(m, __shfl_xor(m, off));
    for (int i = start + lane; i < end; i += 64) {
      int s = clampi(sorted_src[i], 0, N_NODES - 1);
      float l = alh[s].x + adh; l = fmaxf(l, 0.2f * l);
      dsum += __expf(l - m);
    }
    for (int off = 32; off >= 1; off >>= 1) dsum += __shfl_xor(dsum, off);
    const float inv = 1.f / dsum;
    if (lane < RSH) {
      float a0 = 0.f, a1 = 0.f;
      for (int i = start; i < end; ++i) {
        int s = clampi(sorted_src[i], 0, N_NODES - 1);
        float l = alh[s].x + adh; l = fmaxf(l, 0.2f * l);
        float w = __expf(l - m) * inv;
        h16x2 hx = u2h(xb32[(size_t)s * RSH + lane]);
        a0 = fmaf(w, (float)hx[0], a0);
        a1 = fmaf(w, (float)hx[1], a1);
      }
      int cols0 = head * HCH + lane * 2;
      float o0 = a0 + bias[cols0];
      float o1 = a1 + bias[cols0 + 1];
      o0 = o0 > 0.f ? o0 : __expf(o0) - 1.f;
      o1 = o1 > 0.f ? o1 : __expf(o1) - 1.f;
      ((uint32*)outp)[(size_t)head * N_NODES * RSH + (size_t)node * RSH + lane] = pkh(o0, o1);
    }
    return;
  }

  // ---- register stage: lane j owns edge j ----
  uint32 s_reg = 0, wpk = 0;
  float e = 0.f;
  {
    int i = start + lane;
    if (i < end) {
      int s = clampi(sorted_src[i], 0, N_NODES - 1);
      s_reg = (uint32)s;
      float l = alh[s].x + adh;
      l = fmaxf(l, 0.2f * l);
      e = __expf(l - ESH);
      wpk = pkh(e, e);
    }
  }
  float dsum = e;
  for (int off = 32; off >= 1; off >>= 1) dsum += __shfl_xor(dsum, off);
  const float inv = 1.f / dsum;

  const int q  = lane / LPR;
  const int cc = lane % LPR;
  const uint32* myx = xb32 + cc * 4;

  h16x2 acc2[4];
#pragma unroll
  for (int k = 0; k < 4; ++k) acc2[k] = u2h(0u);

  // ---- batch 0: edges 0..31 ----
  {
    int b0 = q, b1 = q + EPI, b2 = q + 2 * EPI, b3 = q + 3 * EPI;
    uint32 s0 = (uint32)__shfl((int)s_reg, b0), w0 = (uint32)__shfl((int)wpk, b0);
    uint32 s1 = (uint32)__shfl((int)s_reg, b1), w1 = (uint32)__shfl((int)wpk, b1);
    uint32 s2 = (uint32)__shfl((int)s_reg, b2), w2 = (uint32)__shfl((int)wpk, b2);
    uint32 s3 = (uint32)__shfl((int)s_reg, b3), w3 = (uint32)__shfl((int)wpk, b3);
    const uint4 v0 = *reinterpret_cast<const uint4*>(myx + (size_t)s0 * RSH);
    const uint4 v1 = *reinterpret_cast<const uint4*>(myx + (size_t)s1 * RSH);
    const uint4 v2 = *reinterpret_cast<const uint4*>(myx + (size_t)s2 * RSH);
    const uint4 v3 = *reinterpret_cast<const uint4*>(myx + (size_t)s3 * RSH);
    h16x2 h0 = u2h(w0), h1 = u2h(w1), h2 = u2h(w2), h3 = u2h(w3);
    acc2[0] += h0 * u2h(v0.x); acc2[1] += h0 * u2h(v0.y);
    acc2[2] += h0 * u2h(v0.z); acc2[3] += h0 * u2h(v0.w);
    acc2[0] += h1 * u2h(v1.x); acc2[1] += h1 * u2h(v1.y);
    acc2[2] += h1 * u2h(v1.z); acc2[3] += h1 * u2h(v1.w);
    acc2[0] += h2 * u2h(v2.x); acc2[1] += h2 * u2h(v2.y);
    acc2[2] += h2 * u2h(v2.z); acc2[3] += h2 * u2h(v2.w);
    acc2[0] += h3 * u2h(v3.x); acc2[1] += h3 * u2h(v3.y);
    acc2[2] += h3 * u2h(v3.z); acc2[3] += h3 * u2h(v3.w);
  }
  // ---- batch 1: edges 32..63 ----
  if (deg > 32) {
    int b0 = 32 + q, b1 = 40 + q, b2 = 48 + q, b3 = 56 + q;
    uint32 s0 = (uint32)__shfl((int)s_reg, b0), w0 = (uint32)__shfl((int)wpk, b0);
    uint32 s1 = (uint32)__shfl((int)s_reg, b1), w1 = (uint32)__shfl((int)wpk, b1);
    uint32 s2 = (uint32)__shfl((int)s_reg, b2), w2 = (uint32)__shfl((int)wpk, b2);
    uint32 s3 = (uint32)__shfl((int)s_reg, b3), w3 = (uint32)__shfl((int)wpk, b3);
    const uint4 v0 = *reinterpret_cast<const uint4*>(myx + (size_t)s0 * RSH);
    const uint4 v1 = *reinterpret_cast<const uint4*>(myx + (size_t)s1 * RSH);
    const uint4 v2 = *reinterpret_cast<const uint4*>(myx + (size_t)s2 * RSH);
    const uint4 v3 = *reinterpret_cast<const uint4*>(myx + (size_t)s3 * RSH);
    h16x2 h0 = u2h(w0), h1 = u2h(w1), h2 = u2h(w2), h3 = u2h(w3);
    acc2[0] += h0 * u2h(v0.x); acc2[1] += h0 * u2h(v0.y);
    acc2[2] += h0 * u2h(v0.z); acc2[3] += h0 * u2h(v0.w);
    acc2[0] += h1 * u2h(v1.x); acc2[1] += h1 * u2h(v1.y);
    acc2[2] += h1 * u2h(v1.z); acc2[3] += h1 * u2h(v1.w);
    acc2[0] += h2 * u2h(v2.x); acc2[1] += h2 * u2h(v2.y);
    acc2[2] += h2 * u2h(v2.z); acc2[3] += h2 * u2h(v2.w);
    acc2[0] += h3 * u2h(v3.x); acc2[1] += h3 * u2h(v3.y);
    acc2[2] += h3 * u2h(v3.z); acc2[3] += h3 * u2h(v3.w);
  }

  // ---- reduce across edge slots ----
#pragma unroll
  for (int k = 0; k < 4; ++k) {
    acc2[k] = u2h((uint32)__shfl_xor((int)h2u(acc2[k]), 8)) + acc2[k];
    acc2[k] = u2h((uint32)__shfl_xor((int)h2u(acc2[k]), 16)) + acc2[k];
    acc2[k] = u2h((uint32)__shfl_xor((int)h2u(acc2[k]), 32)) + acc2[k];
  }

  // ---- epilogue: fold 1/denom, bias + ELU + store ----
  if (q == 0) {
    float o[8];
#pragma unroll
    for (int k = 0; k < 4; ++k) {
      o[2 * k]     = (float)acc2[k][0] * inv + bias[head * HCH + cc * 8 + 2 * k];
      o[2 * k + 1] = (float)acc2[k][1] * inv + bias[head * HCH + cc * 8 + 2 * k + 1];
    }
#pragma unroll
    for (int k = 0; k < 8; ++k) o[k] = o[k] > 0.f ? o[k] : __expf(o[k]) - 1.f;
    uint4 u;
    u.x = pkh(o[0], o[1]); u.y = pkh(o[2], o[3]);
    u.z = pkh(o[4], o[5]); u.w = pkh(o[6], o[7]);
    *reinterpret_cast<uint4*>((uint32*)outp + (size_t)head * N_NODES * RSH +
                              (size_t)node * RSH + cc * 4) = u;
  }
}

// ------------- agg LAYER 2: one wave per node, interleaved buffers, f32 out -------------
__global__ __launch_bounds__(256) void agg_full_kernel(
    const ushort* __restrict__ xh, const float* __restrict__ al,
    const int* __restrict__ row_start, const int* __restrict__ sorted_src,
    const float* __restrict__ bias, float* __restrict__ outp) {
  constexpr int HC = 64;
  constexpr int LPR = HC / 8;          // 8 lanes per 128B row
  constexpr int RS  = HC / 2;          // 32 dwords per row
  const int wid = (blockIdx.x * blockDim.x + threadIdx.x) >> 6;
  const int lane = threadIdx.x & 63;
  if (wid >= N_NODES) return;
  const float4* al4 = (const float4*)al;
  const uint32* xb32 = (const uint32*)xh;
  int start = row_start[wid], end = row_start[wid + 1];
  start = clampi(start, 0, EA);
  end   = clampi(end, start, EA);
  const int deg = end - start;
  float4 mya = al4[wid];
  const float ad0 = mya.z, ad1 = mya.w;
  const float ESH = 2.7725887f;

  if (deg > 64) {
    float m0 = -1e30f, m1 = -1e30f, d0 = 0.f, d1 = 0.f;
    for (int i = start + lane; i < end; i += 64) {
      int s = clampi(sorted_src[i], 0, N_NODES - 1);
      float4 a = al4[s];
      float l0 = a.x + ad0; l0 = fmaxf(l0, 0.2f * l0);
      float l1 = a.y + ad1; l1 = fmaxf(l1, 0.2f * l1);
      m0 = fmaxf(m0, l0); m1 = fmaxf(m1, l1);
    }
    for (int off = 32; off >= 1; off >>= 1) {
      m0 = fmaxf(m0, __shfl_xor(m0, off));
      m1 = fmaxf(m1, __shfl_xor(m1, off));
    }
    for (int i = start + lane; i < end; i += 64) {
      int s = clampi(sorted_src[i], 0, N_NODES - 1);
      float4 a = al4[s];
      float l0 = a.x + ad0; l0 = fmaxf(l0, 0.2f * l0);
      float l1 = a.y + ad1; l1 = fmaxf(l1, 0.2f * l1);
      d0 += __expf(l0 - m0); d1 += __expf(l1 - m1);
    }
    for (int off = 32; off >= 1; off >>= 1) {
      d0 += __shfl_xor(d0, off);
      d1 += __shfl_xor(d1, off);
    }
    const float inv0 = 1.f / d0, inv1 = 1.f / d1;
    const int cols0 = lane * 2;
    const int head = cols0 >= 32;
    const float invh = head ? inv1 : inv0;
    const float mh = head ? m1 : m0;
    const float adh = head ? ad1 : ad0;
    if (lane < RS) {
      float a0 = 0.f, a1 = 0.f;
      for (int i = start; i < end; ++i) {
        int s = clampi(sorted_src[i], 0, N_NODES - 1);
        float lv = (head ? al4[s].y : al4[s].x) + adh;
        lv = fmaxf(lv, 0.2f * lv);
        float w = __expf(lv - mh) * invh;
        h16x2 hx = u2h(xb32[(size_t)s * RS + lane]);
        a0 = fmaf(w, (float)hx[0], a0);
        a1 = fmaf(w, (float)hx[1], a1);
      }
      float o0 = a0 + bias[cols0];
      float o1 = a1 + bias[cols0 + 1];
      o0 = o0 > 0.f ? o0 : __expf(o0) - 1.f;
      o1 = o1 > 0.f ? o1 : __expf(o1) - 1.f;
      *reinterpret_cast<float2*>(outp + (size_t)wid * HC + cols0) = make_float2(o0, o1);
    }
    return;
  }

  // ---- register stage: lane j owns edge j; both heads' weights in regs ----
  uint32 s_reg = 0, wpk0 = 0, wpk1 = 0;
  float e0 = 0.f, e1 = 0.f;
  {
    int i = start + lane;
    if (i < end) {
      int s = clampi(sorted_src[i], 0, N_NODES - 1);
      s_reg = (uint32)s;
      float4 a = al4[s];
      float l0 = a.x + ad0; l0 = fmaxf(l0, 0.2f * l0);
      float l1 = a.y + ad1; l1 = fmaxf(l1, 0.2f * l1);
      e0 = __expf(l0 - ESH);
      e1 = __expf(l1 - ESH);
      wpk0 = pkh(e0, e0);
      wpk1 = pkh(e1, e1);
    }
  }
  float d0 = e0, d1 = e1;
  for (int off = 32; off >= 1; off >>= 1) {
    d0 += __shfl_xor(d0, off);
    d1 += __shfl_xor(d1, off);
  }
  const float inv0 = 1.f / d0, inv1 = 1.f / d1;

  const int q  = lane / LPR;
  const int cc = lane % LPR;
  const int hd = cc >> 2;              // cols [0,32) head0, [32,64) head1
  const uint32* myx = xb32 + cc * 4;

  h16x2 acc2[4];
#pragma unroll
  for (int k = 0; k < 4; ++k) acc2[k] = u2h(0u);

#pragma unroll
  for (int bat = 0; bat < 2; ++bat) {
    if (bat == 1 && deg <= 32) break;
    int jb = bat * 32;
    int b0 = jb + q, b1 = jb + 8 + q, b2 = jb + 16 + q, b3 = jb + 24 + q;
    uint32 s0 = (uint32)__shfl((int)s_reg, b0);
    uint32 s1 = (uint32)__shfl((int)s_reg, b1);
    uint32 s2 = (uint32)__shfl((int)s_reg, b2);
    uint32 s3 = (uint32)__shfl((int)s_reg, b3);
    uint32 wa0 = (uint32)__shfl((int)wpk0, b0), wb0 = (uint32)__shfl((int)wpk1, b0);
    uint32 wa1 = (uint32)__shfl((int)wpk0, b1), wb1 = (uint32)__shfl((int)wpk1, b1);
    uint32 wa2 = (uint32)__shfl((int)wpk0, b2), wb2 = (uint32)__shfl((int)wpk1, b2);
    uint32 wa3 = (uint32)__shfl((int)wpk0, b3), wb3 = (uint32)__shfl((int)wpk1, b3);
    const uint4 v0 = *reinterpret_cast<const uint4*>(myx + (size_t)s0 * RS);
    const uint4 v1 = *reinterpret_cast<const uint4*>(myx + (size_t)s1 * RS);
    const uint4 v2 = *reinterpret_cast<const uint4*>(myx + (size_t)s2 * RS);
    const uint4 v3 = *reinterpret_cast<const uint4*>(myx + (size_t)s3 * RS);
    h16x2 h0 = u2h(hd ? wb0 : wa0), h1 = u2h(hd ? wb1 : wa1);
    h16x2 h2 = u2h(hd ? wb2 : wa2), h3 = u2h(hd ? wb3 : wa3);
    acc2[0] += h0 * u2h(v0.x); acc2[1] += h0 * u2h(v0.y);
    acc2[2] += h0 * u2h(v0.z); acc2[3] += h0 * u2h(v0.w);
    acc2[0] += h1 * u2h(v1.x); acc2[1] += h1 * u2h(v1.y);
    acc2[2] += h1 * u2h(v1.z); acc2[3] += h1 * u2h(v1.w);
    acc2[0] += h2 * u2h(v2.x); acc2[1] += h2 * u2h(v2.y);
    acc2[2] += h2 * u2h(v2.z); acc2[3] += h2 * u2h(v2.w);
    acc2[0] += h3 * u2h(v3.x); acc2[1] += h3 * u2h(v3.y);
    acc2[2] += h3 * u2h(v3.z); acc2[3] += h3 * u2h(v3.w);
  }

#pragma unroll
  for (int k = 0; k < 4; ++k) {
    acc2[k] = u2h((uint32)__shfl_xor((int)h2u(acc2[k]), 8)) + acc2[k];
    acc2[k] = u2h((uint32)__shfl_xor((int)h2u(acc2[k]), 16)) + acc2[k];
    acc2[k] = u2h((uint32)__shfl_xor((int)h2u(acc2[k]), 32)) + acc2[k];
  }

  if (q == 0) {
    const float invh = hd ? inv1 : inv0;
    float o[8];
#pragma unroll
    for (int k = 0; k < 4; ++k) {
      o[2 * k]     = (float)acc2[k][0] * invh + bias[cc * 8 + 2 * k];
      o[2 * k + 1] = (float)acc2[k][1] * invh + bias[cc * 8 + 2 * k + 1];
    }
#pragma unroll
    for (int k = 0; k < 8; ++k) o[k] = o[k] > 0.f ? o[k] : __expf(o[k]) - 1.f;
    float* op = outp + (size_t)wid * HC + cc * 8;
    *reinterpret_cast<float4*>(op)     = make_float4(o[0], o[1], o[2], o[3]);
    *reinterpret_cast<float4*>(op + 4) = make_float4(o[4], o[5], o[6], o[7]);
  }
}

extern "C" void kernel_launch(void* const* d_in, const int* in_sizes, int n_in,
                              void* d_out, int out_size, void* d_ws, size_t ws_size,
                              hipStream_t stream) {
  const float* x      = (const float*)d_in[0];
  const int*   ei     = (const int*)d_in[1];
  const float* W1     = (const float*)d_in[2];
  const float* a_src1 = (const float*)d_in[3];
  const float* a_dst1 = (const float*)d_in[4];
  const float* b1     = (const float*)d_in[5];
  const float* W2     = (const float*)d_in[6];
  const float* a_src2 = (const float*)d_in[7];
  const float* a_dst2 = (const float*)d_in[8];
  const float* b2     = (const float*)d_in[9];
  float* out = (float*)d_out;

  char* ws = (char*)d_ws;
  size_t off = 0;
  auto alloc = [&](size_t bytes) {
    void* p = ws + off;
    off = (off + bytes + 255) & ~(size_t)255;
    return p;
  };
  ushort* xh1       = (ushort*)alloc((size_t)N_NODES * 128 * 2);  // fp16 xp1, [2][N][64]
  ushort* h1h       = (ushort*)alloc((size_t)N_NODES * 128 * 2);  // fp16 h1,  [2][N][64]
  ushort* xh2       = (ushort*)alloc((size_t)N_NODES * 64 * 2);   // fp16 xp2, [N][64]
  float*  al1       = (float*)alloc((size_t)N_NODES * 4 * 4);     // float2[2][N]
  float*  al2       = (float*)alloc((size_t)N_NODES * 4 * 4);     // float4[N]
  int*    row_start = (int*)alloc((size_t)(N_NODES + 1) * 4);
  int*    bcur      = (int*)alloc(NBUCK * 4);
  int*    sorted_src= (int*)alloc((size_t)EA * 4);
  uint32* ebuf      = (uint32*)h1h;   // alias: h1h not live until agg1

  const int* src = ei;
  const int* dst = ei + N_EDGES;

  const int agg1Blocks = (2 * N_NODES) / 4;          // 25000: 4 waves/block, XCD-partitioned
  const int agg2Blocks = (N_NODES * 64) / 256;       // one wave per node
  const int partBlocks = (N_EDGES + EPB - 1) / EPB;
  const int gemmBlocks = (N_NODES + 63) / 64;

  // ---- CSR by destination ----
  hipMemsetAsync(bcur, 0, NBUCK * 4, stream);
  partA_kernel<<<partBlocks, 256, 0, stream>>>(src, dst, bcur, ebuf);
  partB2_kernel<<<NBUCK, 256, 0, stream>>>(bcur, ebuf, row_start, sorted_src);

  // ---- layer 1: head-blocked + XCD-partitioned agg ----
  gemm_mfma_kernel<128, false, true, true><<<gemmBlocks, 256, 0, stream>>>(
      x, W1, a_src1, a_dst1, xh1, al1, out + (size_t)N_NODES * 64, N_NODES);
  agg_split_kernel<64><<<agg1Blocks, 256, 0, stream>>>(xh1, al1, row_start, sorted_src, b1, h1h);

  // ---- layer 2: interleaved (single wave per node; small working set) ----
  gemm_mfma_kernel<64, true, false, false><<<gemmBlocks, 256, 0, stream>>>(
      h1h, W2, a_src2, a_dst2, xh2, al2, nullptr, N_NODES);
  agg_full_kernel<<<agg2Blocks, 256, 0, stream>>>(xh2, al2, row_start, sorted_src, b2, out);
}